// Round 2
// baseline (233.705 us; speedup 1.0000x reference)
//
#include <hip/hip_runtime.h>
#include <cstdint>

#define DEV static __device__ __forceinline__

typedef __bf16 bf16x8 __attribute__((ext_vector_type(8)));
typedef __bf16 bf16x4 __attribute__((ext_vector_type(4)));
typedef short  s16x4  __attribute__((ext_vector_type(4)));
typedef float  f32x4  __attribute__((ext_vector_type(4)));

DEV unsigned short f32_bf16(float f) {
  union { float f; unsigned u; } v; v.f = f;
  unsigned r = v.u + 0x7FFFu + ((v.u >> 16) & 1u);
  return (unsigned short)(r >> 16);
}

DEV void gload16(const void* g, void* lds) {
  __builtin_amdgcn_global_load_lds((__attribute__((address_space(1))) void*)g,
                                   (__attribute__((address_space(3))) void*)lds,
                                   16, 0, 0);
}

DEV float bcast_lane(float v, int srclane) {
  union { float f; int i; } u; u.f = v;
  u.i = __builtin_amdgcn_ds_bpermute(srclane << 2, u.i);
  return u.f;
}

// 16x16x16 bf16 MFMA: A[m=lane&15][k=quad*4+j], B[k=quad*4+j][n=lane&15],
// C/D col=lane&15 row=quad*4+r. P (from S^T C-layout) feeds A directly.
DEV f32x4 mfma16_bf16(bf16x4 a, bf16x4 b, f32x4 c) {
  union { bf16x4 h; s16x4 s; } ua, ub; ua.h = a; ub.h = b;
#if __has_builtin(__builtin_amdgcn_mfma_f32_16x16x16bf16_1k)
  return __builtin_amdgcn_mfma_f32_16x16x16bf16_1k(ua.s, ub.s, c, 0, 0, 0);
#else
  f32x4 d;
  asm("v_mfma_f32_16x16x16_bf16 %0, %1, %2, %3" : "=v"(d) : "v"(ua.s), "v"(ub.s), "v"(c));
  return d;
#endif
}

// ---------------- elementwise cast fp32 -> bf16 ----------------
__global__ void cast_bf16(const float* __restrict__ x, unsigned short* __restrict__ y) {
  int i = blockIdx.x * 256 + threadIdx.x;
  float4 v = ((const float4*)x)[i];
  uint2 o;
  o.x = (unsigned)f32_bf16(v.x) | ((unsigned)f32_bf16(v.y) << 16);
  o.y = (unsigned)f32_bf16(v.z) | ((unsigned)f32_bf16(v.w) << 16);
  ((uint2*)y)[i] = o;
}

// ---------------- tiled transpose-cast: W[K][N] fp32 -> WT[N][K] bf16 ----------------
__global__ void transpose_cast(const float* __restrict__ W, unsigned short* __restrict__ WT,
                               int K, int N) {
  __shared__ float t[64][65];
  int k0 = blockIdx.x * 64, n0 = blockIdx.y * 64;
  int tn = threadIdx.x & 63, tk = threadIdx.x >> 6;
#pragma unroll
  for (int i = 0; i < 64; i += 4)
    t[tk + i][tn] = W[(size_t)(k0 + tk + i) * N + n0 + tn];
  __syncthreads();
  int k2 = (threadIdx.x & 31) * 2, n = threadIdx.x >> 5;
#pragma unroll
  for (int i = 0; i < 64; i += 8) {
    int nn = n + i;
    unsigned o = (unsigned)f32_bf16(t[k2][nn]) | ((unsigned)f32_bf16(t[k2 + 1][nn]) << 16);
    *(unsigned*)&WT[(size_t)(n0 + nn) * K + k0 + k2] = o;
  }
}

// ---------------- mask uniformity check ----------------
__global__ void mask_check(const float* __restrict__ m, int* __restrict__ flag) {
  size_t i = ((size_t)blockIdx.x * 256 + threadIdx.x) * 4;
  float4 v = *(const float4*)(m + i);
  if (v.x != 1.0f || v.y != 1.0f || v.z != 1.0f || v.w != 1.0f) atomicOr(flag, 1);
}

// ---------------- GEMM: C[M][N] = A[M][K] * BT[N][K]^T ----------------
// MODE 0: fp32 C. MODE 2: scatter Qb/Kb [b,h,s,d], VTb [b,h,d,s] (TN must be 128).
// VTb s-index is permuted within each 128-block: f(k)=p*32+q4*8+half*4+j so the attn
// kernel can read PV B-fragments (two 16x16x16 tiles) with a single b128.
template <int MODE, int TN>
__global__ void __launch_bounds__(256) gemm_bt(const unsigned short* __restrict__ A,
                                               const unsigned short* __restrict__ BT,
                                               float* __restrict__ Cout,
                                               unsigned short* __restrict__ Qb,
                                               unsigned short* __restrict__ Kb,
                                               unsigned short* __restrict__ VTb,
                                               int M, int N, int K) {
  constexpr int NT = TN / 32;
  __shared__ __align__(16) unsigned short As[128 * 32];
  __shared__ __align__(16) unsigned short Bs[TN * 32];
  const int tid = threadIdx.x, wave = tid >> 6, lane = tid & 63;
  const int l = lane & 15, quad = lane >> 4;
  const int wm = (wave & 1) * 64, wn = (wave >> 1) * (TN >> 1);
  const int bm = blockIdx.x, bn = blockIdx.y;

  const int srowA = wave * 32 + (lane >> 2);
  const int sswzA = ((lane & 3) ^ (srowA & 3)) * 8;
  const int srowB = (TN == 128) ? srowA : (wave * 16 + (lane >> 2));
  const int sswzB = ((lane & 3) ^ (srowB & 3)) * 8;
  const unsigned short* pA = A + (size_t)(bm * 128 + srowA) * K + sswzA;
  const unsigned short* pB = BT + (size_t)(bn * TN + srowB) * K + sswzB;
  unsigned short* ldsA0 = &As[(wave * 32) * 32];
  unsigned short* ldsA1 = &As[(wave * 32 + 16) * 32];
  unsigned short* ldsB0 = &Bs[((TN == 128 ? wave * 32 : wave * 16)) * 32];
  unsigned short* ldsB1 = &Bs[(wave * 32 + 16) * 32];  // TN==128 only

  f32x4 acc[4][NT];
#pragma unroll
  for (int i = 0; i < 4; i++)
#pragma unroll
    for (int j = 0; j < NT; j++) { f32x4 z = {0.f, 0.f, 0.f, 0.f}; acc[i][j] = z; }

  for (int kt = 0; kt < K; kt += 32) {
    __syncthreads();
    gload16(pA, ldsA0);
    gload16(pA + (size_t)16 * K, ldsA1);
    gload16(pB, ldsB0);
    if (TN == 128) gload16(pB + (size_t)16 * K, ldsB1);
    pA += 32; pB += 32;
    __syncthreads();
    bf16x8 af[4], bv[NT];
#pragma unroll
    for (int mt = 0; mt < 4; mt++) {
      int r = wm + mt * 16 + l;
      af[mt] = *(const bf16x8*)&As[r * 32 + ((quad ^ (r & 3)) * 8)];
    }
#pragma unroll
    for (int nt = 0; nt < NT; nt++) {
      int r = wn + nt * 16 + l;
      bv[nt] = *(const bf16x8*)&Bs[r * 32 + ((quad ^ (r & 3)) * 8)];
    }
#pragma unroll
    for (int mt = 0; mt < 4; mt++)
#pragma unroll
      for (int nt = 0; nt < NT; nt++)
        acc[mt][nt] = __builtin_amdgcn_mfma_f32_16x16x32_bf16(af[mt], bv[nt], acc[mt][nt], 0, 0, 0);
  }

  // epilogue: C/D layout col = lane&15, row = quad*4 + r
#pragma unroll
  for (int nt = 0; nt < NT; nt++) {
    const int col = bn * TN + wn + nt * 16 + l;
#pragma unroll
    for (int mt = 0; mt < 4; mt++) {
      const int row0 = bm * 128 + wm + mt * 16 + quad * 4;
      if (MODE == 0) {
#pragma unroll
        for (int r = 0; r < 4; r++)
          Cout[(size_t)(row0 + r) * N + col] = acc[mt][nt][r];
      } else {
        const int bb = row0 >> 11, s = row0 & 2047;
        if (col < 2048) {
          unsigned short* dst = (col < 1024) ? Qb : Kb;
          const int c = col & 1023;
          const size_t off = ((size_t)(bb * 16 + (c >> 6)) * 2048 + s) * 64 + (c & 63);
#pragma unroll
          for (int r = 0; r < 4; r++)
            dst[off + (size_t)r * 64] = f32_bf16(acc[mt][nt][r]);
        } else {
          const int c = col - 2048;
          // permute s within its 128-block: keep bits 6,5,1,0; bits 3,2 -> 4,3; bit 4 -> 2
          const int sl = s & 127;
          const int snew = (s & ~127) | (sl & 0x63) | ((sl & 0x0C) << 1) | ((sl & 0x10) >> 2);
          const size_t off = ((size_t)(bb * 16 + (c >> 6)) * 64 + (c & 63)) * 2048 + snew;
          bf16x4 pk;
#pragma unroll
          for (int r = 0; r < 4; r++) pk[r] = (__bf16)acc[mt][nt][r];
          *(bf16x4*)&VTb[off] = pk;
        }
      }
    }
  }
}

// ---------------- fused flash attention, S^T form, P-in-registers, double-buffered ----------------
// grid 512 = 16 q-tiles x 32 (b,h); block 512 = 8 waves = 4 wq (32 q-rows) x 2 wk (64 k-rows).
// The k-split halves per-wave LDS reads (K: 8 b128, V: 8 b128 per kt) vs the q-only split;
// wk halves combine O/l once at the end through the freed KV buffer.
// blockIdx decode puts all 16 q-blocks of one (b,h) on the same XCD (bid%8 round-robin).
// One barrier per K-iteration: tile kt+2 is staged into the buffer consumed at iter kt.
__global__ void __launch_bounds__(512, 4) attn(const unsigned short* __restrict__ Qb,
                                               const unsigned short* __restrict__ Kb,
                                               const unsigned short* __restrict__ VTb,
                                               const float* __restrict__ mask,
                                               const float* __restrict__ emb,
                                               const int* __restrict__ mflag,
                                               unsigned short* __restrict__ ctx) {
  // two buffers, each: K tile (128x64) + V^T tile (64x128)
  __shared__ __align__(16) unsigned short KV[2][16384];
  __shared__ float biasLUT[512];

  const float LOG2E = 1.4426950408889634f;
  const float c1 = 0.125f * LOG2E;
  const float C2 = 10000.0f * LOG2E;
  const int tid = threadIdx.x, wave = tid >> 6, lane = tid & 63;
  const int l = lane & 15, quad = lane >> 4;
  const int wq = wave & 3, wk = wave >> 2;
  const int bh = blockIdx.x & 31, qt = blockIdx.x >> 5;
  const int b = bh >> 4, h = bh & 15;
  const int q0 = qt * 128;

  {
    int i = tid;  // 512 threads cover the 512-entry LUT exactly once
    int rel = i - 256;
    int rp = rel < 0 ? -rel : rel;
    int off = rp < 8 ? rp
                     : 8 + (rp >= 12) + (rp >= 16) + (rp >= 23) + (rp >= 32) +
                           (rp >= 46) + (rp >= 64) + (rp >= 91);
    int bucket = (rel > 0 ? 16 : 0) + off;
    biasLUT[i] = emb[bucket * 16 + h] * LOG2E;
  }
  const float satL = emb[15 * 16 + h] * LOG2E;
  const float satH = emb[31 * 16 + h] * LOG2E;
  const int masked = *mflag;

  const unsigned short* qb  = Qb  + ((size_t)(b * 16 + h) * 2048 + q0) * 64;
  const unsigned short* kb  = Kb  + (size_t)(b * 16 + h) * 2048 * 64;
  const unsigned short* vtb = VTb + (size_t)(b * 16 + h) * 64 * 2048;
  const float* mbase = mask + (size_t)b * 2048 * 2048;

  const int rw8 = lane >> 3, c8s = lane & 7;    // K/Q staging: 8 chunks/row
  const int rw16 = lane >> 4, c16 = lane & 15;  // V staging: 16 chunks/row

  // ---- prologue: Q -> buf1 K-region, tile0 K/V -> buf0 ----
#pragma unroll
  for (int j = 0; j < 2; j++) {
    int row = wave * 16 + j * 8 + rw8;
    gload16(qb + (size_t)row * 64 + ((c8s ^ (row & 7)) * 8), &KV[1][(wave * 16 + j * 8) * 64]);
  }
#pragma unroll
  for (int j = 0; j < 2; j++) {
    int row = wave * 16 + j * 8 + rw8;
    gload16(kb + (size_t)row * 64 + ((c8s ^ (row & 7)) * 8), &KV[0][(wave * 16 + j * 8) * 64]);
  }
#pragma unroll
  for (int j = 0; j < 2; j++) {
    int drow = wave * 8 + j * 4 + rw16;
    gload16(vtb + (size_t)drow * 2048 + ((c16 ^ (drow & 7)) * 8),
            &KV[0][8192 + (wave * 8 + j * 4) * 128]);
  }
  __syncthreads();

  // each wave reads its 32 Q rows (staged region of buf1)
  bf16x8 qf[2][2];
#pragma unroll
  for (int mtq = 0; mtq < 2; mtq++)
#pragma unroll
    for (int ks = 0; ks < 2; ks++) {
      int row = wq * 32 + mtq * 16 + l;
      qf[mtq][ks] = *(const bf16x8*)&KV[1][row * 64 + (((ks * 4 + quad) ^ (row & 7)) * 8)];
    }
  __syncthreads();  // Q reads complete before buf1 is overwritten with tile1

  // ---- stage tile1 -> buf1 ----
#pragma unroll
  for (int j = 0; j < 2; j++) {
    int row = wave * 16 + j * 8 + rw8;
    gload16(kb + (size_t)(128 + row) * 64 + ((c8s ^ (row & 7)) * 8),
            &KV[1][(wave * 16 + j * 8) * 64]);
  }
#pragma unroll
  for (int j = 0; j < 2; j++) {
    int drow = wave * 8 + j * 4 + rw16;
    gload16(vtb + (size_t)drow * 2048 + 128 + ((c16 ^ (drow & 7)) * 8),
            &KV[1][8192 + (wave * 8 + j * 4) * 128]);
  }

  float lr[2] = {0.f, 0.f};
  f32x4 Oa[2][4];
#pragma unroll
  for (int mtq = 0; mtq < 2; mtq++)
#pragma unroll
    for (int dt = 0; dt < 4; dt++) { f32x4 z = {0.f, 0.f, 0.f, 0.f}; Oa[mtq][dt] = z; }

  for (int kt = 0; kt < 16; kt++) {
    const int k0 = kt * 128;
    const unsigned short* Ks  = KV[kt & 1];
    const unsigned short* VTs = KV[kt & 1] + 8192;

    // ---- S^T = K Q^T (wave's 64 k-rows x 32 q-cols), scale+bias(+mask), exp2 ----
    const int d0 = k0 - q0;
    const bool sat = (d0 >= 256) || (d0 <= -256);
    const float bias_u = d0 > 0 ? satH : satL;
    const int ibase = 256 + d0 + wk * 64 + quad * 4 - wq * 32 - l;
    bf16x4 pa[2][4];

#pragma unroll
    for (int ntk = 0; ntk < 4; ntk++) {
      int row = wk * 64 + ntk * 16 + l;
      bf16x8 kf0 = *(const bf16x8*)&Ks[row * 64 + ((quad ^ (row & 7)) * 8)];
      bf16x8 kf1 = *(const bf16x8*)&Ks[row * 64 + (((4 + quad) ^ (row & 7)) * 8)];
#pragma unroll
      for (int mtq = 0; mtq < 2; mtq++) {
        f32x4 s = {0.f, 0.f, 0.f, 0.f};
        s = __builtin_amdgcn_mfma_f32_16x16x32_bf16(kf0, qf[mtq][0], s, 0, 0, 0);
        s = __builtin_amdgcn_mfma_f32_16x16x32_bf16(kf1, qf[mtq][1], s, 0, 0, 0);

        const int ib = ibase + ntk * 16 - mtq * 16;
        if (!masked) {
          if (sat) {
#pragma unroll
            for (int r = 0; r < 4; r++) s[r] = fmaf(s[r], c1, bias_u);
          } else {
#pragma unroll
            for (int r = 0; r < 4; r++) s[r] = fmaf(s[r], c1, biasLUT[ib + r]);
          }
        } else {
          const int qg = q0 + wq * 32 + mtq * 16 + l;
          const int kg = k0 + wk * 64 + ntk * 16 + quad * 4;
          float4 mv4 = *(const float4*)&mbase[(size_t)qg * 2048 + kg];
#pragma unroll
          for (int r = 0; r < 4; r++) {
            float mv = r == 0 ? mv4.x : (r == 1 ? mv4.y : (r == 2 ? mv4.z : mv4.w));
            float bias = sat ? bias_u : biasLUT[ib + r];
            s[r] = fmaf(s[r], mv * c1, fmaf(mv, C2, bias - C2));
          }
        }
        bf16x4 pk;
        float ls = 0.f;
#pragma unroll
        for (int r = 0; r < 4; r++) {
          float p = __builtin_amdgcn_exp2f(s[r]);  // softmax shift-invariance: no max needed
          ls += p;
          pk[r] = (__bf16)p;
        }
        lr[mtq] += ls;
        pa[mtq][ntk] = pk;
      }
    }

    // ---- O += P V via 16x16x16 MFMA; V read as b128 thanks to permuted layout ----
#pragma unroll
    for (int dt = 0; dt < 4; dt++) {
      int row = dt * 16 + l;
      union { bf16x8 w; struct { bf16x4 lo, hi; } h; } v0, v1;
      v0.w = *(const bf16x8*)&VTs[row * 128 + (((wk * 8 + quad) ^ (l & 7)) * 8)];
      v1.w = *(const bf16x8*)&VTs[row * 128 + (((wk * 8 + 4 + quad) ^ (l & 7)) * 8)];
#pragma unroll
      for (int mtq = 0; mtq < 2; mtq++) {
        Oa[mtq][dt] = mfma16_bf16(pa[mtq][0], v0.h.lo, Oa[mtq][dt]);
        Oa[mtq][dt] = mfma16_bf16(pa[mtq][1], v0.h.hi, Oa[mtq][dt]);
        Oa[mtq][dt] = mfma16_bf16(pa[mtq][2], v1.h.lo, Oa[mtq][dt]);
        Oa[mtq][dt] = mfma16_bf16(pa[mtq][3], v1.h.hi, Oa[mtq][dt]);
      }
    }

    // ---- one barrier: all reads of this buffer done + next tile's loads landed ----
    __syncthreads();
    if (kt + 2 < 16) {
      const int kn = (kt + 2) * 128;
      unsigned short* dst = (unsigned short*)KV[kt & 1];
#pragma unroll
      for (int j = 0; j < 2; j++) {
        int row = wave * 16 + j * 8 + rw8;
        gload16(kb + (size_t)(kn + row) * 64 + ((c8s ^ (row & 7)) * 8),
                &dst[(wave * 16 + j * 8) * 64]);
      }
#pragma unroll
      for (int j = 0; j < 2; j++) {
        int drow = wave * 8 + j * 4 + rw16;
        gload16(vtb + (size_t)drow * 2048 + kn + ((c16 ^ (drow & 7)) * 8),
                &dst[8192 + (wave * 8 + j * 4) * 128]);
      }
    }
  }

  // ---- cross-wave (wk) reduction through freed KV, then normalize + store ----
  float* Of = (float*)KV;       // 8192 floats = 32KB (q 0..127 x d 0..63)
  float* Lf = Of + 8192;        // 128 floats
  if (wk == 1) {
#pragma unroll
    for (int mtq = 0; mtq < 2; mtq++) {
      float v = lr[mtq];
      v += __shfl_xor(v, 16);
      v += __shfl_xor(v, 32);
      if (quad == 0) Lf[wq * 32 + mtq * 16 + l] = v;
#pragma unroll
      for (int dt = 0; dt < 4; dt++)
#pragma unroll
        for (int r = 0; r < 4; r++)
          Of[(wq * 32 + mtq * 16 + quad * 4 + r) * 64 + dt * 16 + l] = Oa[mtq][dt][r];
    }
  }
  __syncthreads();
  if (wk == 0) {
#pragma unroll
    for (int mtq = 0; mtq < 2; mtq++) {
      float v = lr[mtq];
      v += __shfl_xor(v, 16);
      v += __shfl_xor(v, 32);
      v += Lf[wq * 32 + mtq * 16 + l];
      const float inv = 1.0f / v;
#pragma unroll
      for (int r = 0; r < 4; r++) {
        float i_bc = bcast_lane(inv, quad * 4 + r);
        const int qg = q0 + wq * 32 + mtq * 16 + quad * 4 + r;
#pragma unroll
        for (int dt = 0; dt < 4; dt++) {
          float o = Oa[mtq][dt][r] +
                    Of[(wq * 32 + mtq * 16 + quad * 4 + r) * 64 + dt * 16 + l];
          ctx[(size_t)(b * 2048 + qg) * 1024 + h * 64 + dt * 16 + l] = f32_bf16(o * i_bc);
        }
      }
    }
  }
}

// ---------------- launch ----------------
extern "C" void kernel_launch(void* const* d_in, const int* in_sizes, int n_in,
                              void* d_out, int out_size, void* d_ws, size_t ws_size,
                              hipStream_t stream) {
  const float* hs   = (const float*)d_in[0];
  const float* mask = (const float*)d_in[1];
  const float* wqkv = (const float*)d_in[2];
  const float* wo   = (const float*)d_in[3];
  const float* emb  = (const float*)d_in[4];
  float* out = (float*)d_out;

  char* ws = (char*)d_ws;
  unsigned short* hB  = (unsigned short*)(ws);               //  8 MB (alias ctx)
  unsigned short* ctx = (unsigned short*)(ws);               //  alias
  unsigned short* wqT = (unsigned short*)(ws + 8388608);     //  6 MB
  unsigned short* woT = (unsigned short*)(ws + 14680064);    //  2 MB
  unsigned short* Qb  = (unsigned short*)(ws + 16777216);    //  8 MB  [b,h,s,d]
  unsigned short* Kb  = (unsigned short*)(ws + 25165824);    //  8 MB  [b,h,s,d]
  unsigned short* VTb = (unsigned short*)(ws + 33554432);    //  8 MB  [b,h,d,s] (s-permuted)
  int* mflag          = (int*)(ws + 41943040);
  if (ws_size < 41943044) return;

  hipMemsetAsync(mflag, 0, 4, stream);
  cast_bf16<<<4096, 256, 0, stream>>>(hs, hB);
  transpose_cast<<<dim3(16, 48), 256, 0, stream>>>(wqkv, wqT, 1024, 3072);
  transpose_cast<<<dim3(16, 16), 256, 0, stream>>>(wo, woT, 1024, 1024);
  mask_check<<<8192, 256, 0, stream>>>(mask, mflag);
  gemm_bt<2, 128><<<dim3(32, 24), 256, 0, stream>>>(hB, wqT, nullptr, Qb, Kb, VTb, 4096, 3072, 1024);
  attn<<<512, 512, 0, stream>>>(Qb, Kb, VTb, mask, emb, mflag, ctx);
  gemm_bt<0, 64><<<dim3(32, 16), 256, 0, stream>>>(ctx, woT, out, nullptr, nullptr, nullptr, 4096, 1024, 1024);
}

// Round 3
// 231.936 us; speedup vs baseline: 1.0076x; 1.0076x over previous
//
#include <hip/hip_runtime.h>
#include <cstdint>

#define DEV static __device__ __forceinline__

typedef __bf16 bf16x8 __attribute__((ext_vector_type(8)));
typedef __bf16 bf16x4 __attribute__((ext_vector_type(4)));
typedef short  s16x4  __attribute__((ext_vector_type(4)));
typedef float  f32x4  __attribute__((ext_vector_type(4)));

DEV unsigned short f32_bf16(float f) {
  union { float f; unsigned u; } v; v.f = f;
  unsigned r = v.u + 0x7FFFu + ((v.u >> 16) & 1u);
  return (unsigned short)(r >> 16);
}

DEV void gload16(const void* g, void* lds) {
  __builtin_amdgcn_global_load_lds((__attribute__((address_space(1))) void*)g,
                                   (__attribute__((address_space(3))) void*)lds,
                                   16, 0, 0);
}

DEV float bcast_lane(float v, int srclane) {
  union { float f; int i; } u; u.f = v;
  u.i = __builtin_amdgcn_ds_bpermute(srclane << 2, u.i);
  return u.f;
}

// 16x16x16 bf16 MFMA: A[m=lane&15][k=quad*4+j], B[k=quad*4+j][n=lane&15],
// C/D col=lane&15 row=quad*4+r. P (from S^T C-layout) feeds A directly.
DEV f32x4 mfma16_bf16(bf16x4 a, bf16x4 b, f32x4 c) {
  union { bf16x4 h; s16x4 s; } ua, ub; ua.h = a; ub.h = b;
#if __has_builtin(__builtin_amdgcn_mfma_f32_16x16x16bf16_1k)
  return __builtin_amdgcn_mfma_f32_16x16x16bf16_1k(ua.s, ub.s, c, 0, 0, 0);
#else
  f32x4 d;
  asm("v_mfma_f32_16x16x16_bf16 %0, %1, %2, %3" : "=v"(d) : "v"(ua.s), "v"(ub.s), "v"(c));
  return d;
#endif
}

// ---------------- elementwise cast fp32 -> bf16 ----------------
__global__ void cast_bf16(const float* __restrict__ x, unsigned short* __restrict__ y) {
  int i = blockIdx.x * 256 + threadIdx.x;
  float4 v = ((const float4*)x)[i];
  uint2 o;
  o.x = (unsigned)f32_bf16(v.x) | ((unsigned)f32_bf16(v.y) << 16);
  o.y = (unsigned)f32_bf16(v.z) | ((unsigned)f32_bf16(v.w) << 16);
  ((uint2*)y)[i] = o;
}

// ---------------- tiled transpose-cast: W[K][N] fp32 -> WT[N][K] bf16 ----------------
__global__ void transpose_cast(const float* __restrict__ W, unsigned short* __restrict__ WT,
                               int K, int N) {
  __shared__ float t[64][65];
  int k0 = blockIdx.x * 64, n0 = blockIdx.y * 64;
  int tn = threadIdx.x & 63, tk = threadIdx.x >> 6;
#pragma unroll
  for (int i = 0; i < 64; i += 4)
    t[tk + i][tn] = W[(size_t)(k0 + tk + i) * N + n0 + tn];
  __syncthreads();
  int k2 = (threadIdx.x & 31) * 2, n = threadIdx.x >> 5;
#pragma unroll
  for (int i = 0; i < 64; i += 8) {
    int nn = n + i;
    unsigned o = (unsigned)f32_bf16(t[k2][nn]) | ((unsigned)f32_bf16(t[k2 + 1][nn]) << 16);
    *(unsigned*)&WT[(size_t)(n0 + nn) * K + k0 + k2] = o;
  }
}

// ---------------- mask uniformity check ----------------
__global__ void mask_check(const float* __restrict__ m, int* __restrict__ flag) {
  size_t i = ((size_t)blockIdx.x * 256 + threadIdx.x) * 4;
  float4 v = *(const float4*)(m + i);
  if (v.x != 1.0f || v.y != 1.0f || v.z != 1.0f || v.w != 1.0f) atomicOr(flag, 1);
}

// ---------------- GEMM: C[M][N] = A[M][K] * BT[N][K]^T ----------------
// MODE 0: fp32 C. MODE 2: scatter Qb/Kb [b,h,s,d], VTb [b,h,d,s] (TN must be 128).
// VTb s-index is permuted within each 128-block: f(k)=p*32+q4*8+half*4+j so the attn
// kernel can read PV B-fragments (two 16x16x16 tiles) with a single b128.
template <int MODE, int TN>
__global__ void __launch_bounds__(256) gemm_bt(const unsigned short* __restrict__ A,
                                               const unsigned short* __restrict__ BT,
                                               float* __restrict__ Cout,
                                               unsigned short* __restrict__ Qb,
                                               unsigned short* __restrict__ Kb,
                                               unsigned short* __restrict__ VTb,
                                               int M, int N, int K) {
  constexpr int NT = TN / 32;
  __shared__ __align__(16) unsigned short As[128 * 32];
  __shared__ __align__(16) unsigned short Bs[TN * 32];
  const int tid = threadIdx.x, wave = tid >> 6, lane = tid & 63;
  const int l = lane & 15, quad = lane >> 4;
  const int wm = (wave & 1) * 64, wn = (wave >> 1) * (TN >> 1);
  const int bm = blockIdx.x, bn = blockIdx.y;

  const int srowA = wave * 32 + (lane >> 2);
  const int sswzA = ((lane & 3) ^ (srowA & 3)) * 8;
  const int srowB = (TN == 128) ? srowA : (wave * 16 + (lane >> 2));
  const int sswzB = ((lane & 3) ^ (srowB & 3)) * 8;
  const unsigned short* pA = A + (size_t)(bm * 128 + srowA) * K + sswzA;
  const unsigned short* pB = BT + (size_t)(bn * TN + srowB) * K + sswzB;
  unsigned short* ldsA0 = &As[(wave * 32) * 32];
  unsigned short* ldsA1 = &As[(wave * 32 + 16) * 32];
  unsigned short* ldsB0 = &Bs[((TN == 128 ? wave * 32 : wave * 16)) * 32];
  unsigned short* ldsB1 = &Bs[(wave * 32 + 16) * 32];  // TN==128 only

  f32x4 acc[4][NT];
#pragma unroll
  for (int i = 0; i < 4; i++)
#pragma unroll
    for (int j = 0; j < NT; j++) { f32x4 z = {0.f, 0.f, 0.f, 0.f}; acc[i][j] = z; }

  for (int kt = 0; kt < K; kt += 32) {
    __syncthreads();
    gload16(pA, ldsA0);
    gload16(pA + (size_t)16 * K, ldsA1);
    gload16(pB, ldsB0);
    if (TN == 128) gload16(pB + (size_t)16 * K, ldsB1);
    pA += 32; pB += 32;
    __syncthreads();
    bf16x8 af[4], bv[NT];
#pragma unroll
    for (int mt = 0; mt < 4; mt++) {
      int r = wm + mt * 16 + l;
      af[mt] = *(const bf16x8*)&As[r * 32 + ((quad ^ (r & 3)) * 8)];
    }
#pragma unroll
    for (int nt = 0; nt < NT; nt++) {
      int r = wn + nt * 16 + l;
      bv[nt] = *(const bf16x8*)&Bs[r * 32 + ((quad ^ (r & 3)) * 8)];
    }
#pragma unroll
    for (int mt = 0; mt < 4; mt++)
#pragma unroll
      for (int nt = 0; nt < NT; nt++)
        acc[mt][nt] = __builtin_amdgcn_mfma_f32_16x16x32_bf16(af[mt], bv[nt], acc[mt][nt], 0, 0, 0);
  }

  // epilogue: C/D layout col = lane&15, row = quad*4 + r
#pragma unroll
  for (int nt = 0; nt < NT; nt++) {
    const int col = bn * TN + wn + nt * 16 + l;
#pragma unroll
    for (int mt = 0; mt < 4; mt++) {
      const int row0 = bm * 128 + wm + mt * 16 + quad * 4;
      if (MODE == 0) {
#pragma unroll
        for (int r = 0; r < 4; r++)
          Cout[(size_t)(row0 + r) * N + col] = acc[mt][nt][r];
      } else {
        const int bb = row0 >> 11, s = row0 & 2047;
        if (col < 2048) {
          unsigned short* dst = (col < 1024) ? Qb : Kb;
          const int c = col & 1023;
          const size_t off = ((size_t)(bb * 16 + (c >> 6)) * 2048 + s) * 64 + (c & 63);
#pragma unroll
          for (int r = 0; r < 4; r++)
            dst[off + (size_t)r * 64] = f32_bf16(acc[mt][nt][r]);
        } else {
          const int c = col - 2048;
          // permute s within its 128-block: keep bits 6,5,1,0; bits 3,2 -> 4,3; bit 4 -> 2
          const int sl = s & 127;
          const int snew = (s & ~127) | (sl & 0x63) | ((sl & 0x0C) << 1) | ((sl & 0x10) >> 2);
          const size_t off = ((size_t)(bb * 16 + (c >> 6)) * 64 + (c & 63)) * 2048 + snew;
          bf16x4 pk;
#pragma unroll
          for (int r = 0; r < 4; r++) pk[r] = (__bf16)acc[mt][nt][r];
          *(bf16x4*)&VTb[off] = pk;
        }
      }
    }
  }
}

// ---------------- fused flash attention, S^T form, P-in-registers, double-buffered ----------------
// grid 512 = 16 q-tiles x 32 (b,h); block 512 = 8 waves = 4 wq (32 q-rows) x 2 wk (64 k-rows).
// The k-split halves per-wave LDS reads (K: 8 b128, V: 8 b128 per kt) vs the q-only split;
// wk halves combine O/l once at the end through the freed KV buffer.
// V b128 halves are extracted with __builtin_shufflevector (register-only) — a union/struct
// extraction here defeats SROA and round-trips through scratch (measured: +16MB HBM writes).
// blockIdx decode puts all 16 q-blocks of one (b,h) on the same XCD (bid%8 round-robin).
// One barrier per K-iteration: tile kt+2 is staged into the buffer consumed at iter kt.
__global__ void __launch_bounds__(512, 4) attn(const unsigned short* __restrict__ Qb,
                                               const unsigned short* __restrict__ Kb,
                                               const unsigned short* __restrict__ VTb,
                                               const float* __restrict__ mask,
                                               const float* __restrict__ emb,
                                               const int* __restrict__ mflag,
                                               unsigned short* __restrict__ ctx) {
  // two buffers, each: K tile (128x64) + V^T tile (64x128)
  __shared__ __align__(16) unsigned short KV[2][16384];
  __shared__ float biasLUT[512];

  const float LOG2E = 1.4426950408889634f;
  const float c1 = 0.125f * LOG2E;
  const float C2 = 10000.0f * LOG2E;
  const int tid = threadIdx.x, wave = tid >> 6, lane = tid & 63;
  const int l = lane & 15, quad = lane >> 4;
  const int wq = wave & 3, wk = wave >> 2;
  const int bh = blockIdx.x & 31, qt = blockIdx.x >> 5;
  const int b = bh >> 4, h = bh & 15;
  const int q0 = qt * 128;

  {
    int i = tid;  // 512 threads cover the 512-entry LUT exactly once
    int rel = i - 256;
    int rp = rel < 0 ? -rel : rel;
    int off = rp < 8 ? rp
                     : 8 + (rp >= 12) + (rp >= 16) + (rp >= 23) + (rp >= 32) +
                           (rp >= 46) + (rp >= 64) + (rp >= 91);
    int bucket = (rel > 0 ? 16 : 0) + off;
    biasLUT[i] = emb[bucket * 16 + h] * LOG2E;
  }
  const float satL = emb[15 * 16 + h] * LOG2E;
  const float satH = emb[31 * 16 + h] * LOG2E;
  const int masked = *mflag;

  const unsigned short* qb  = Qb  + ((size_t)(b * 16 + h) * 2048 + q0) * 64;
  const unsigned short* kb  = Kb  + (size_t)(b * 16 + h) * 2048 * 64;
  const unsigned short* vtb = VTb + (size_t)(b * 16 + h) * 64 * 2048;
  const float* mbase = mask + (size_t)b * 2048 * 2048;

  const int rw8 = lane >> 3, c8s = lane & 7;    // K/Q staging: 8 chunks/row
  const int rw16 = lane >> 4, c16 = lane & 15;  // V staging: 16 chunks/row

  // ---- prologue: Q -> buf1 K-region, tile0 K/V -> buf0 ----
#pragma unroll
  for (int j = 0; j < 2; j++) {
    int row = wave * 16 + j * 8 + rw8;
    gload16(qb + (size_t)row * 64 + ((c8s ^ (row & 7)) * 8), &KV[1][(wave * 16 + j * 8) * 64]);
  }
#pragma unroll
  for (int j = 0; j < 2; j++) {
    int row = wave * 16 + j * 8 + rw8;
    gload16(kb + (size_t)row * 64 + ((c8s ^ (row & 7)) * 8), &KV[0][(wave * 16 + j * 8) * 64]);
  }
#pragma unroll
  for (int j = 0; j < 2; j++) {
    int drow = wave * 8 + j * 4 + rw16;
    gload16(vtb + (size_t)drow * 2048 + ((c16 ^ (drow & 7)) * 8),
            &KV[0][8192 + (wave * 8 + j * 4) * 128]);
  }
  __syncthreads();

  // each wave reads its 32 Q rows (staged region of buf1)
  bf16x8 qf[2][2];
#pragma unroll
  for (int mtq = 0; mtq < 2; mtq++)
#pragma unroll
    for (int ks = 0; ks < 2; ks++) {
      int row = wq * 32 + mtq * 16 + l;
      qf[mtq][ks] = *(const bf16x8*)&KV[1][row * 64 + (((ks * 4 + quad) ^ (row & 7)) * 8)];
    }
  __syncthreads();  // Q reads complete before buf1 is overwritten with tile1

  // ---- stage tile1 -> buf1 ----
#pragma unroll
  for (int j = 0; j < 2; j++) {
    int row = wave * 16 + j * 8 + rw8;
    gload16(kb + (size_t)(128 + row) * 64 + ((c8s ^ (row & 7)) * 8),
            &KV[1][(wave * 16 + j * 8) * 64]);
  }
#pragma unroll
  for (int j = 0; j < 2; j++) {
    int drow = wave * 8 + j * 4 + rw16;
    gload16(vtb + (size_t)drow * 2048 + 128 + ((c16 ^ (drow & 7)) * 8),
            &KV[1][8192 + (wave * 8 + j * 4) * 128]);
  }

  float lr[2] = {0.f, 0.f};
  f32x4 Oa[2][4];
#pragma unroll
  for (int mtq = 0; mtq < 2; mtq++)
#pragma unroll
    for (int dt = 0; dt < 4; dt++) { f32x4 z = {0.f, 0.f, 0.f, 0.f}; Oa[mtq][dt] = z; }

  for (int kt = 0; kt < 16; kt++) {
    const int k0 = kt * 128;
    const unsigned short* Ks  = KV[kt & 1];
    const unsigned short* VTs = KV[kt & 1] + 8192;

    // ---- S^T = K Q^T (wave's 64 k-rows x 32 q-cols), scale+bias(+mask), exp2 ----
    const int d0 = k0 - q0;
    const bool sat = (d0 >= 256) || (d0 <= -256);
    const float bias_u = d0 > 0 ? satH : satL;
    const int ibase = 256 + d0 + wk * 64 + quad * 4 - wq * 32 - l;
    bf16x4 pa[2][4];

#pragma unroll
    for (int ntk = 0; ntk < 4; ntk++) {
      int row = wk * 64 + ntk * 16 + l;
      bf16x8 kf0 = *(const bf16x8*)&Ks[row * 64 + ((quad ^ (row & 7)) * 8)];
      bf16x8 kf1 = *(const bf16x8*)&Ks[row * 64 + (((4 + quad) ^ (row & 7)) * 8)];
#pragma unroll
      for (int mtq = 0; mtq < 2; mtq++) {
        f32x4 s = {0.f, 0.f, 0.f, 0.f};
        s = __builtin_amdgcn_mfma_f32_16x16x32_bf16(kf0, qf[mtq][0], s, 0, 0, 0);
        s = __builtin_amdgcn_mfma_f32_16x16x32_bf16(kf1, qf[mtq][1], s, 0, 0, 0);

        const int ib = ibase + ntk * 16 - mtq * 16;
        if (!masked) {
          if (sat) {
#pragma unroll
            for (int r = 0; r < 4; r++) s[r] = fmaf(s[r], c1, bias_u);
          } else {
#pragma unroll
            for (int r = 0; r < 4; r++) s[r] = fmaf(s[r], c1, biasLUT[ib + r]);
          }
        } else {
          const int qg = q0 + wq * 32 + mtq * 16 + l;
          const int kg = k0 + wk * 64 + ntk * 16 + quad * 4;
          float4 mv4 = *(const float4*)&mbase[(size_t)qg * 2048 + kg];
#pragma unroll
          for (int r = 0; r < 4; r++) {
            float mv = r == 0 ? mv4.x : (r == 1 ? mv4.y : (r == 2 ? mv4.z : mv4.w));
            float bias = sat ? bias_u : biasLUT[ib + r];
            s[r] = fmaf(s[r], mv * c1, fmaf(mv, C2, bias - C2));
          }
        }
        bf16x4 pk;
        float ls = 0.f;
#pragma unroll
        for (int r = 0; r < 4; r++) {
          float p = __builtin_amdgcn_exp2f(s[r]);  // softmax shift-invariance: no max needed
          ls += p;
          pk[r] = (__bf16)p;
        }
        lr[mtq] += ls;
        pa[mtq][ntk] = pk;
      }
    }

    // ---- O += P V via 16x16x16 MFMA; V read as b128 thanks to permuted layout ----
#pragma unroll
    for (int dt = 0; dt < 4; dt++) {
      int row = dt * 16 + l;
      bf16x8 w0 = *(const bf16x8*)&VTs[row * 128 + (((wk * 8 + quad) ^ (l & 7)) * 8)];
      bf16x8 w1 = *(const bf16x8*)&VTs[row * 128 + (((wk * 8 + 4 + quad) ^ (l & 7)) * 8)];
      bf16x4 v00 = __builtin_shufflevector(w0, w0, 0, 1, 2, 3);
      bf16x4 v01 = __builtin_shufflevector(w0, w0, 4, 5, 6, 7);
      bf16x4 v10 = __builtin_shufflevector(w1, w1, 0, 1, 2, 3);
      bf16x4 v11 = __builtin_shufflevector(w1, w1, 4, 5, 6, 7);
#pragma unroll
      for (int mtq = 0; mtq < 2; mtq++) {
        Oa[mtq][dt] = mfma16_bf16(pa[mtq][0], v00, Oa[mtq][dt]);
        Oa[mtq][dt] = mfma16_bf16(pa[mtq][1], v01, Oa[mtq][dt]);
        Oa[mtq][dt] = mfma16_bf16(pa[mtq][2], v10, Oa[mtq][dt]);
        Oa[mtq][dt] = mfma16_bf16(pa[mtq][3], v11, Oa[mtq][dt]);
      }
    }

    // ---- one barrier: all reads of this buffer done + next tile's loads landed ----
    __syncthreads();
    if (kt + 2 < 16) {
      const int kn = (kt + 2) * 128;
      unsigned short* dst = (unsigned short*)KV[kt & 1];
#pragma unroll
      for (int j = 0; j < 2; j++) {
        int row = wave * 16 + j * 8 + rw8;
        gload16(kb + (size_t)(kn + row) * 64 + ((c8s ^ (row & 7)) * 8),
                &dst[(wave * 16 + j * 8) * 64]);
      }
#pragma unroll
      for (int j = 0; j < 2; j++) {
        int drow = wave * 8 + j * 4 + rw16;
        gload16(vtb + (size_t)drow * 2048 + kn + ((c16 ^ (drow & 7)) * 8),
                &dst[8192 + (wave * 8 + j * 4) * 128]);
      }
    }
  }

  // ---- cross-wave (wk) reduction through freed KV, then normalize + store ----
  float* Of = (float*)KV;       // 8192 floats = 32KB (q 0..127 x d 0..63)
  float* Lf = Of + 8192;        // 128 floats
  if (wk == 1) {
#pragma unroll
    for (int mtq = 0; mtq < 2; mtq++) {
      float v = lr[mtq];
      v += __shfl_xor(v, 16);
      v += __shfl_xor(v, 32);
      if (quad == 0) Lf[wq * 32 + mtq * 16 + l] = v;
#pragma unroll
      for (int dt = 0; dt < 4; dt++)
#pragma unroll
        for (int r = 0; r < 4; r++)
          Of[(wq * 32 + mtq * 16 + quad * 4 + r) * 64 + dt * 16 + l] = Oa[mtq][dt][r];
    }
  }
  __syncthreads();
  if (wk == 0) {
#pragma unroll
    for (int mtq = 0; mtq < 2; mtq++) {
      float v = lr[mtq];
      v += __shfl_xor(v, 16);
      v += __shfl_xor(v, 32);
      v += Lf[wq * 32 + mtq * 16 + l];
      const float inv = 1.0f / v;
#pragma unroll
      for (int r = 0; r < 4; r++) {
        float i_bc = bcast_lane(inv, quad * 4 + r);
        const int qg = q0 + wq * 32 + mtq * 16 + quad * 4 + r;
#pragma unroll
        for (int dt = 0; dt < 4; dt++) {
          float o = Oa[mtq][dt][r] +
                    Of[(wq * 32 + mtq * 16 + quad * 4 + r) * 64 + dt * 16 + l];
          ctx[(size_t)(b * 2048 + qg) * 1024 + h * 64 + dt * 16 + l] = f32_bf16(o * i_bc);
        }
      }
    }
  }
}

// ---------------- launch ----------------
extern "C" void kernel_launch(void* const* d_in, const int* in_sizes, int n_in,
                              void* d_out, int out_size, void* d_ws, size_t ws_size,
                              hipStream_t stream) {
  const float* hs   = (const float*)d_in[0];
  const float* mask = (const float*)d_in[1];
  const float* wqkv = (const float*)d_in[2];
  const float* wo   = (const float*)d_in[3];
  const float* emb  = (const float*)d_in[4];
  float* out = (float*)d_out;

  char* ws = (char*)d_ws;
  unsigned short* hB  = (unsigned short*)(ws);               //  8 MB (alias ctx)
  unsigned short* ctx = (unsigned short*)(ws);               //  alias
  unsigned short* wqT = (unsigned short*)(ws + 8388608);     //  6 MB
  unsigned short* woT = (unsigned short*)(ws + 14680064);    //  2 MB
  unsigned short* Qb  = (unsigned short*)(ws + 16777216);    //  8 MB  [b,h,s,d]
  unsigned short* Kb  = (unsigned short*)(ws + 25165824);    //  8 MB  [b,h,s,d]
  unsigned short* VTb = (unsigned short*)(ws + 33554432);    //  8 MB  [b,h,d,s] (s-permuted)
  int* mflag          = (int*)(ws + 41943040);
  if (ws_size < 41943044) return;

  hipMemsetAsync(mflag, 0, 4, stream);
  cast_bf16<<<4096, 256, 0, stream>>>(hs, hB);
  transpose_cast<<<dim3(16, 48), 256, 0, stream>>>(wqkv, wqT, 1024, 3072);
  transpose_cast<<<dim3(16, 16), 256, 0, stream>>>(wo, woT, 1024, 1024);
  mask_check<<<8192, 256, 0, stream>>>(mask, mflag);
  gemm_bt<2, 128><<<dim3(32, 24), 256, 0, stream>>>(hB, wqT, nullptr, Qb, Kb, VTb, 4096, 3072, 1024);
  attn<<<512, 512, 0, stream>>>(Qb, Kb, VTb, mask, emb, mflag, ctx);
  gemm_bt<0, 64><<<dim3(32, 16), 256, 0, stream>>>(ctx, woT, out, nullptr, nullptr, nullptr, 4096, 1024, 1024);
}

// Round 4
// 219.636 us; speedup vs baseline: 1.0641x; 1.0560x over previous
//
#include <hip/hip_runtime.h>
#include <cstdint>

#define DEV static __device__ __forceinline__

typedef __bf16 bf16x8 __attribute__((ext_vector_type(8)));
typedef __bf16 bf16x4 __attribute__((ext_vector_type(4)));
typedef short  s16x4  __attribute__((ext_vector_type(4)));
typedef float  f32x4  __attribute__((ext_vector_type(4)));

DEV unsigned short f32_bf16(float f) {
  union { float f; unsigned u; } v; v.f = f;
  unsigned r = v.u + 0x7FFFu + ((v.u >> 16) & 1u);
  return (unsigned short)(r >> 16);
}

DEV void gload16(const void* g, void* lds) {
  __builtin_amdgcn_global_load_lds((__attribute__((address_space(1))) void*)g,
                                   (__attribute__((address_space(3))) void*)lds,
                                   16, 0, 0);
}

DEV float bcast_lane(float v, int srclane) {
  union { float f; int i; } u; u.f = v;
  u.i = __builtin_amdgcn_ds_bpermute(srclane << 2, u.i);
  return u.f;
}

// 16x16x16 bf16 MFMA: A[m=lane&15][k=quad*4+j], B[k=quad*4+j][n=lane&15],
// C/D col=lane&15 row=quad*4+r. P (from S^T C-layout) feeds A directly.
DEV f32x4 mfma16_bf16(bf16x4 a, bf16x4 b, f32x4 c) {
  union { bf16x4 h; s16x4 s; } ua, ub; ua.h = a; ub.h = b;
#if __has_builtin(__builtin_amdgcn_mfma_f32_16x16x16bf16_1k)
  return __builtin_amdgcn_mfma_f32_16x16x16bf16_1k(ua.s, ub.s, c, 0, 0, 0);
#else
  f32x4 d;
  asm("v_mfma_f32_16x16x16_bf16 %0, %1, %2, %3" : "=v"(d) : "v"(ua.s), "v"(ub.s), "v"(c));
  return d;
#endif
}

// ---------------- elementwise cast fp32 -> bf16 ----------------
__global__ void cast_bf16(const float* __restrict__ x, unsigned short* __restrict__ y) {
  int i = blockIdx.x * 256 + threadIdx.x;
  float4 v = ((const float4*)x)[i];
  uint2 o;
  o.x = (unsigned)f32_bf16(v.x) | ((unsigned)f32_bf16(v.y) << 16);
  o.y = (unsigned)f32_bf16(v.z) | ((unsigned)f32_bf16(v.w) << 16);
  ((uint2*)y)[i] = o;
}

// ---------------- tiled transpose-cast: W[K][N] fp32 -> WT[N][K] bf16 ----------------
__global__ void transpose_cast(const float* __restrict__ W, unsigned short* __restrict__ WT,
                               int K, int N) {
  __shared__ float t[64][65];
  int k0 = blockIdx.x * 64, n0 = blockIdx.y * 64;
  int tn = threadIdx.x & 63, tk = threadIdx.x >> 6;
#pragma unroll
  for (int i = 0; i < 64; i += 4)
    t[tk + i][tn] = W[(size_t)(k0 + tk + i) * N + n0 + tn];
  __syncthreads();
  int k2 = (threadIdx.x & 31) * 2, n = threadIdx.x >> 5;
#pragma unroll
  for (int i = 0; i < 64; i += 8) {
    int nn = n + i;
    unsigned o = (unsigned)f32_bf16(t[k2][nn]) | ((unsigned)f32_bf16(t[k2 + 1][nn]) << 16);
    *(unsigned*)&WT[(size_t)(n0 + nn) * K + k0 + k2] = o;
  }
}

// ---------------- mask uniformity check ----------------
__global__ void mask_check(const float* __restrict__ m, int* __restrict__ flag) {
  size_t i = ((size_t)blockIdx.x * 256 + threadIdx.x) * 4;
  float4 v = *(const float4*)(m + i);
  if (v.x != 1.0f || v.y != 1.0f || v.z != 1.0f || v.w != 1.0f) atomicOr(flag, 1);
}

// ---------------- GEMM: C[M][N] = A[M][K] * BT[N][K]^T ----------------
// MODE 0: fp32 C. MODE 2: scatter Qb/Kb [b,h,s,d], VTb [b,h,d,s] (TN must be 128).
// VTb s-index is permuted within each 128-block: f(k)=p*32+q4*8+half*4+j so the attn
// kernel can read PV B-fragments (two 16x16x16 tiles) with a single b128.
template <int MODE, int TN>
__global__ void __launch_bounds__(256) gemm_bt(const unsigned short* __restrict__ A,
                                               const unsigned short* __restrict__ BT,
                                               float* __restrict__ Cout,
                                               unsigned short* __restrict__ Qb,
                                               unsigned short* __restrict__ Kb,
                                               unsigned short* __restrict__ VTb,
                                               int M, int N, int K) {
  constexpr int NT = TN / 32;
  __shared__ __align__(16) unsigned short As[128 * 32];
  __shared__ __align__(16) unsigned short Bs[TN * 32];
  const int tid = threadIdx.x, wave = tid >> 6, lane = tid & 63;
  const int l = lane & 15, quad = lane >> 4;
  const int wm = (wave & 1) * 64, wn = (wave >> 1) * (TN >> 1);
  const int bm = blockIdx.x, bn = blockIdx.y;

  const int srowA = wave * 32 + (lane >> 2);
  const int sswzA = ((lane & 3) ^ (srowA & 3)) * 8;
  const int srowB = (TN == 128) ? srowA : (wave * 16 + (lane >> 2));
  const int sswzB = ((lane & 3) ^ (srowB & 3)) * 8;
  const unsigned short* pA = A + (size_t)(bm * 128 + srowA) * K + sswzA;
  const unsigned short* pB = BT + (size_t)(bn * TN + srowB) * K + sswzB;
  unsigned short* ldsA0 = &As[(wave * 32) * 32];
  unsigned short* ldsA1 = &As[(wave * 32 + 16) * 32];
  unsigned short* ldsB0 = &Bs[((TN == 128 ? wave * 32 : wave * 16)) * 32];
  unsigned short* ldsB1 = &Bs[(wave * 32 + 16) * 32];  // TN==128 only

  f32x4 acc[4][NT];
#pragma unroll
  for (int i = 0; i < 4; i++)
#pragma unroll
    for (int j = 0; j < NT; j++) { f32x4 z = {0.f, 0.f, 0.f, 0.f}; acc[i][j] = z; }

  for (int kt = 0; kt < K; kt += 32) {
    __syncthreads();
    gload16(pA, ldsA0);
    gload16(pA + (size_t)16 * K, ldsA1);
    gload16(pB, ldsB0);
    if (TN == 128) gload16(pB + (size_t)16 * K, ldsB1);
    pA += 32; pB += 32;
    __syncthreads();
    bf16x8 af[4], bv[NT];
#pragma unroll
    for (int mt = 0; mt < 4; mt++) {
      int r = wm + mt * 16 + l;
      af[mt] = *(const bf16x8*)&As[r * 32 + ((quad ^ (r & 3)) * 8)];
    }
#pragma unroll
    for (int nt = 0; nt < NT; nt++) {
      int r = wn + nt * 16 + l;
      bv[nt] = *(const bf16x8*)&Bs[r * 32 + ((quad ^ (r & 3)) * 8)];
    }
#pragma unroll
    for (int mt = 0; mt < 4; mt++)
#pragma unroll
      for (int nt = 0; nt < NT; nt++)
        acc[mt][nt] = __builtin_amdgcn_mfma_f32_16x16x32_bf16(af[mt], bv[nt], acc[mt][nt], 0, 0, 0);
  }

  // epilogue: C/D layout col = lane&15, row = quad*4 + r
#pragma unroll
  for (int nt = 0; nt < NT; nt++) {
    const int col = bn * TN + wn + nt * 16 + l;
#pragma unroll
    for (int mt = 0; mt < 4; mt++) {
      const int row0 = bm * 128 + wm + mt * 16 + quad * 4;
      if (MODE == 0) {
#pragma unroll
        for (int r = 0; r < 4; r++)
          Cout[(size_t)(row0 + r) * N + col] = acc[mt][nt][r];
      } else {
        const int bb = row0 >> 11, s = row0 & 2047;
        if (col < 2048) {
          unsigned short* dst = (col < 1024) ? Qb : Kb;
          const int c = col & 1023;
          const size_t off = ((size_t)(bb * 16 + (c >> 6)) * 2048 + s) * 64 + (c & 63);
#pragma unroll
          for (int r = 0; r < 4; r++)
            dst[off + (size_t)r * 64] = f32_bf16(acc[mt][nt][r]);
        } else {
          const int c = col - 2048;
          // permute s within its 128-block: keep bits 6,5,1,0; bits 3,2 -> 4,3; bit 4 -> 2
          const int sl = s & 127;
          const int snew = (s & ~127) | (sl & 0x63) | ((sl & 0x0C) << 1) | ((sl & 0x10) >> 2);
          const size_t off = ((size_t)(bb * 16 + (c >> 6)) * 64 + (c & 63)) * 2048 + snew;
          bf16x4 pk;
#pragma unroll
          for (int r = 0; r < 4; r++) pk[r] = (__bf16)acc[mt][nt][r];
          *(bf16x4*)&VTb[off] = pk;
        }
      }
    }
  }
}

// ---------------- fused flash attention, S^T form, P-in-registers, double-buffered ----------------
// grid 512 = 16 q-tiles x 32 (b,h); block 512 = 8 waves = 4 wq (32 q-rows) x 2 wk (64 k-rows).
// The k-split halves per-wave LDS reads (K: 8 b128, V: 8 b128 per kt) vs the q-only split;
// wk halves combine O/l once at the end through the freed KV buffer.
// QK and PV are interleaved per ntk-PAIR so only pa[2][2] (8 VGPRs) is live at a time:
// the pa[2][4] variant exceeded the 64-arch-VGPR budget (Oa/s take the AGPR side of the
// unified file under __launch_bounds__(512,4)) and spilled ~64B/thread to scratch
// (measured: +16MB HBM WRITE_SIZE, MfmaUtil 32->27).
// blockIdx decode puts all 16 q-blocks of one (b,h) on the same XCD (bid%8 round-robin).
// One barrier per K-iteration: tile kt+2 is staged into the buffer consumed at iter kt.
__global__ void __launch_bounds__(512, 4) attn(const unsigned short* __restrict__ Qb,
                                               const unsigned short* __restrict__ Kb,
                                               const unsigned short* __restrict__ VTb,
                                               const float* __restrict__ mask,
                                               const float* __restrict__ emb,
                                               const int* __restrict__ mflag,
                                               unsigned short* __restrict__ ctx) {
  // two buffers, each: K tile (128x64) + V^T tile (64x128)
  __shared__ __align__(16) unsigned short KV[2][16384];
  __shared__ float biasLUT[512];

  const float LOG2E = 1.4426950408889634f;
  const float c1 = 0.125f * LOG2E;
  const float C2 = 10000.0f * LOG2E;
  const int tid = threadIdx.x, wave = tid >> 6, lane = tid & 63;
  const int l = lane & 15, quad = lane >> 4;
  const int wq = wave & 3, wk = wave >> 2;
  const int bh = blockIdx.x & 31, qt = blockIdx.x >> 5;
  const int b = bh >> 4, h = bh & 15;
  const int q0 = qt * 128;

  {
    int i = tid;  // 512 threads cover the 512-entry LUT exactly once
    int rel = i - 256;
    int rp = rel < 0 ? -rel : rel;
    int off = rp < 8 ? rp
                     : 8 + (rp >= 12) + (rp >= 16) + (rp >= 23) + (rp >= 32) +
                           (rp >= 46) + (rp >= 64) + (rp >= 91);
    int bucket = (rel > 0 ? 16 : 0) + off;
    biasLUT[i] = emb[bucket * 16 + h] * LOG2E;
  }
  const float satL = emb[15 * 16 + h] * LOG2E;
  const float satH = emb[31 * 16 + h] * LOG2E;
  const int masked = *mflag;

  const unsigned short* qb  = Qb  + ((size_t)(b * 16 + h) * 2048 + q0) * 64;
  const unsigned short* kb  = Kb  + (size_t)(b * 16 + h) * 2048 * 64;
  const unsigned short* vtb = VTb + (size_t)(b * 16 + h) * 64 * 2048;
  const float* mbase = mask + (size_t)b * 2048 * 2048;

  const int rw8 = lane >> 3, c8s = lane & 7;    // K/Q staging: 8 chunks/row
  const int rw16 = lane >> 4, c16 = lane & 15;  // V staging: 16 chunks/row

  // ---- prologue: Q -> buf1 K-region, tile0 K/V -> buf0 ----
#pragma unroll
  for (int j = 0; j < 2; j++) {
    int row = wave * 16 + j * 8 + rw8;
    gload16(qb + (size_t)row * 64 + ((c8s ^ (row & 7)) * 8), &KV[1][(wave * 16 + j * 8) * 64]);
  }
#pragma unroll
  for (int j = 0; j < 2; j++) {
    int row = wave * 16 + j * 8 + rw8;
    gload16(kb + (size_t)row * 64 + ((c8s ^ (row & 7)) * 8), &KV[0][(wave * 16 + j * 8) * 64]);
  }
#pragma unroll
  for (int j = 0; j < 2; j++) {
    int drow = wave * 8 + j * 4 + rw16;
    gload16(vtb + (size_t)drow * 2048 + ((c16 ^ (drow & 7)) * 8),
            &KV[0][8192 + (wave * 8 + j * 4) * 128]);
  }
  __syncthreads();

  // each wave reads its 32 Q rows (staged region of buf1)
  bf16x8 qf[2][2];
#pragma unroll
  for (int mtq = 0; mtq < 2; mtq++)
#pragma unroll
    for (int ks = 0; ks < 2; ks++) {
      int row = wq * 32 + mtq * 16 + l;
      qf[mtq][ks] = *(const bf16x8*)&KV[1][row * 64 + (((ks * 4 + quad) ^ (row & 7)) * 8)];
    }
  __syncthreads();  // Q reads complete before buf1 is overwritten with tile1

  // ---- stage tile1 -> buf1 ----
#pragma unroll
  for (int j = 0; j < 2; j++) {
    int row = wave * 16 + j * 8 + rw8;
    gload16(kb + (size_t)(128 + row) * 64 + ((c8s ^ (row & 7)) * 8),
            &KV[1][(wave * 16 + j * 8) * 64]);
  }
#pragma unroll
  for (int j = 0; j < 2; j++) {
    int drow = wave * 8 + j * 4 + rw16;
    gload16(vtb + (size_t)drow * 2048 + 128 + ((c16 ^ (drow & 7)) * 8),
            &KV[1][8192 + (wave * 8 + j * 4) * 128]);
  }

  float lr[2] = {0.f, 0.f};
  f32x4 Oa[2][4];
#pragma unroll
  for (int mtq = 0; mtq < 2; mtq++)
#pragma unroll
    for (int dt = 0; dt < 4; dt++) { f32x4 z = {0.f, 0.f, 0.f, 0.f}; Oa[mtq][dt] = z; }

  for (int kt = 0; kt < 16; kt++) {
    const int k0 = kt * 128;
    const unsigned short* Ks  = KV[kt & 1];
    const unsigned short* VTs = KV[kt & 1] + 8192;

    const int d0 = k0 - q0;
    const bool sat = (d0 >= 256) || (d0 <= -256);
    const float bias_u = d0 > 0 ? satH : satL;
    const int ibase = 256 + d0 + wk * 64 + quad * 4 - wq * 32 - l;

    // ---- interleaved per ntk-pair: S^T (2 k-slabs) then PV for those slabs ----
#pragma unroll
    for (int p = 0; p < 2; p++) {
      bf16x4 pa[2][2];
#pragma unroll
      for (int t = 0; t < 2; t++) {
        const int ntk = p * 2 + t;
        int row = wk * 64 + ntk * 16 + l;
        bf16x8 kf0 = *(const bf16x8*)&Ks[row * 64 + ((quad ^ (row & 7)) * 8)];
        bf16x8 kf1 = *(const bf16x8*)&Ks[row * 64 + (((4 + quad) ^ (row & 7)) * 8)];
#pragma unroll
        for (int mtq = 0; mtq < 2; mtq++) {
          f32x4 s = {0.f, 0.f, 0.f, 0.f};
          s = __builtin_amdgcn_mfma_f32_16x16x32_bf16(kf0, qf[mtq][0], s, 0, 0, 0);
          s = __builtin_amdgcn_mfma_f32_16x16x32_bf16(kf1, qf[mtq][1], s, 0, 0, 0);

          const int ib = ibase + ntk * 16 - mtq * 16;
          if (!masked) {
            if (sat) {
#pragma unroll
              for (int r = 0; r < 4; r++) s[r] = fmaf(s[r], c1, bias_u);
            } else {
#pragma unroll
              for (int r = 0; r < 4; r++) s[r] = fmaf(s[r], c1, biasLUT[ib + r]);
            }
          } else {
            const int qg = q0 + wq * 32 + mtq * 16 + l;
            const int kg = k0 + wk * 64 + ntk * 16 + quad * 4;
            float4 mv4 = *(const float4*)&mbase[(size_t)qg * 2048 + kg];
#pragma unroll
            for (int r = 0; r < 4; r++) {
              float mv = r == 0 ? mv4.x : (r == 1 ? mv4.y : (r == 2 ? mv4.z : mv4.w));
              float bias = sat ? bias_u : biasLUT[ib + r];
              s[r] = fmaf(s[r], mv * c1, fmaf(mv, C2, bias - C2));
            }
          }
          bf16x4 pk;
          float ls = 0.f;
#pragma unroll
          for (int r = 0; r < 4; r++) {
            float pv = __builtin_amdgcn_exp2f(s[r]);  // softmax shift-invariance: no max needed
            ls += pv;
            pk[r] = (__bf16)pv;
          }
          lr[mtq] += ls;
          pa[mtq][t] = pk;
        }
      }

      // ---- O += P V for this pair; one b128 per dt covers both k-slabs ----
#pragma unroll
      for (int dt = 0; dt < 4; dt++) {
        int row = dt * 16 + l;
        bf16x8 w = *(const bf16x8*)&VTs[row * 128 + (((wk * 8 + p * 4 + quad) ^ (l & 7)) * 8)];
        bf16x4 vlo = __builtin_shufflevector(w, w, 0, 1, 2, 3);
        bf16x4 vhi = __builtin_shufflevector(w, w, 4, 5, 6, 7);
#pragma unroll
        for (int mtq = 0; mtq < 2; mtq++) {
          Oa[mtq][dt] = mfma16_bf16(pa[mtq][0], vlo, Oa[mtq][dt]);
          Oa[mtq][dt] = mfma16_bf16(pa[mtq][1], vhi, Oa[mtq][dt]);
        }
      }
    }

    // ---- one barrier: all reads of this buffer done + next tile's loads landed ----
    __syncthreads();
    if (kt + 2 < 16) {
      const int kn = (kt + 2) * 128;
      unsigned short* dst = (unsigned short*)KV[kt & 1];
#pragma unroll
      for (int j = 0; j < 2; j++) {
        int row = wave * 16 + j * 8 + rw8;
        gload16(kb + (size_t)(kn + row) * 64 + ((c8s ^ (row & 7)) * 8),
                &dst[(wave * 16 + j * 8) * 64]);
      }
#pragma unroll
      for (int j = 0; j < 2; j++) {
        int drow = wave * 8 + j * 4 + rw16;
        gload16(vtb + (size_t)drow * 2048 + kn + ((c16 ^ (drow & 7)) * 8),
                &dst[8192 + (wave * 8 + j * 4) * 128]);
      }
    }
  }

  // ---- cross-wave (wk) reduction through freed KV, then normalize + store ----
  float* Of = (float*)KV;       // 8192 floats = 32KB (q 0..127 x d 0..63)
  float* Lf = Of + 8192;        // 128 floats
  if (wk == 1) {
#pragma unroll
    for (int mtq = 0; mtq < 2; mtq++) {
      float v = lr[mtq];
      v += __shfl_xor(v, 16);
      v += __shfl_xor(v, 32);
      if (quad == 0) Lf[wq * 32 + mtq * 16 + l] = v;
#pragma unroll
      for (int dt = 0; dt < 4; dt++)
#pragma unroll
        for (int r = 0; r < 4; r++)
          Of[(wq * 32 + mtq * 16 + quad * 4 + r) * 64 + dt * 16 + l] = Oa[mtq][dt][r];
    }
  }
  __syncthreads();
  if (wk == 0) {
#pragma unroll
    for (int mtq = 0; mtq < 2; mtq++) {
      float v = lr[mtq];
      v += __shfl_xor(v, 16);
      v += __shfl_xor(v, 32);
      v += Lf[wq * 32 + mtq * 16 + l];
      const float inv = 1.0f / v;
#pragma unroll
      for (int r = 0; r < 4; r++) {
        float i_bc = bcast_lane(inv, quad * 4 + r);
        const int qg = q0 + wq * 32 + mtq * 16 + quad * 4 + r;
#pragma unroll
        for (int dt = 0; dt < 4; dt++) {
          float o = Oa[mtq][dt][r] +
                    Of[(wq * 32 + mtq * 16 + quad * 4 + r) * 64 + dt * 16 + l];
          ctx[(size_t)(b * 2048 + qg) * 1024 + h * 64 + dt * 16 + l] = f32_bf16(o * i_bc);
        }
      }
    }
  }
}

// ---------------- launch ----------------
extern "C" void kernel_launch(void* const* d_in, const int* in_sizes, int n_in,
                              void* d_out, int out_size, void* d_ws, size_t ws_size,
                              hipStream_t stream) {
  const float* hs   = (const float*)d_in[0];
  const float* mask = (const float*)d_in[1];
  const float* wqkv = (const float*)d_in[2];
  const float* wo   = (const float*)d_in[3];
  const float* emb  = (const float*)d_in[4];
  float* out = (float*)d_out;

  char* ws = (char*)d_ws;
  unsigned short* hB  = (unsigned short*)(ws);               //  8 MB (alias ctx)
  unsigned short* ctx = (unsigned short*)(ws);               //  alias
  unsigned short* wqT = (unsigned short*)(ws + 8388608);     //  6 MB
  unsigned short* woT = (unsigned short*)(ws + 14680064);    //  2 MB
  unsigned short* Qb  = (unsigned short*)(ws + 16777216);    //  8 MB  [b,h,s,d]
  unsigned short* Kb  = (unsigned short*)(ws + 25165824);    //  8 MB  [b,h,s,d]
  unsigned short* VTb = (unsigned short*)(ws + 33554432);    //  8 MB  [b,h,d,s] (s-permuted)
  int* mflag          = (int*)(ws + 41943040);
  if (ws_size < 41943044) return;

  hipMemsetAsync(mflag, 0, 4, stream);
  cast_bf16<<<4096, 256, 0, stream>>>(hs, hB);
  transpose_cast<<<dim3(16, 48), 256, 0, stream>>>(wqkv, wqT, 1024, 3072);
  transpose_cast<<<dim3(16, 16), 256, 0, stream>>>(wo, woT, 1024, 1024);
  mask_check<<<8192, 256, 0, stream>>>(mask, mflag);
  gemm_bt<2, 128><<<dim3(32, 24), 256, 0, stream>>>(hB, wqT, nullptr, Qb, Kb, VTb, 4096, 3072, 1024);
  attn<<<512, 512, 0, stream>>>(Qb, Kb, VTb, mask, emb, mflag, ctx);
  gemm_bt<0, 64><<<dim3(32, 16), 256, 0, stream>>>(ctx, woT, out, nullptr, nullptr, nullptr, 4096, 1024, 1024);
}

// Round 5
// 215.989 us; speedup vs baseline: 1.0820x; 1.0169x over previous
//
#include <hip/hip_runtime.h>
#include <cstdint>

#define DEV static __device__ __forceinline__

typedef __bf16 bf16x8 __attribute__((ext_vector_type(8)));
typedef __bf16 bf16x4 __attribute__((ext_vector_type(4)));
typedef short  s16x4  __attribute__((ext_vector_type(4)));
typedef float  f32x4  __attribute__((ext_vector_type(4)));

DEV unsigned short f32_bf16(float f) {
  union { float f; unsigned u; } v; v.f = f;
  unsigned r = v.u + 0x7FFFu + ((v.u >> 16) & 1u);
  return (unsigned short)(r >> 16);
}

DEV void gload16(const void* g, void* lds) {
  __builtin_amdgcn_global_load_lds((__attribute__((address_space(1))) void*)g,
                                   (__attribute__((address_space(3))) void*)lds,
                                   16, 0, 0);
}

DEV float bcast_lane(float v, int srclane) {
  union { float f; int i; } u; u.f = v;
  u.i = __builtin_amdgcn_ds_bpermute(srclane << 2, u.i);
  return u.f;
}

// 16x16x16 bf16 MFMA: A[m=lane&15][k=quad*4+j], B[k=quad*4+j][n=lane&15],
// C/D col=lane&15 row=quad*4+r. P (from S^T C-layout) feeds A directly.
DEV f32x4 mfma16_bf16(bf16x4 a, bf16x4 b, f32x4 c) {
  union { bf16x4 h; s16x4 s; } ua, ub; ua.h = a; ub.h = b;
#if __has_builtin(__builtin_amdgcn_mfma_f32_16x16x16bf16_1k)
  return __builtin_amdgcn_mfma_f32_16x16x16bf16_1k(ua.s, ub.s, c, 0, 0, 0);
#else
  f32x4 d;
  asm("v_mfma_f32_16x16x16_bf16 %0, %1, %2, %3" : "=v"(d) : "v"(ua.s), "v"(ub.s), "v"(c));
  return d;
#endif
}

// ---------------- elementwise cast fp32 -> bf16 ----------------
__global__ void cast_bf16(const float* __restrict__ x, unsigned short* __restrict__ y) {
  int i = blockIdx.x * 256 + threadIdx.x;
  float4 v = ((const float4*)x)[i];
  uint2 o;
  o.x = (unsigned)f32_bf16(v.x) | ((unsigned)f32_bf16(v.y) << 16);
  o.y = (unsigned)f32_bf16(v.z) | ((unsigned)f32_bf16(v.w) << 16);
  ((uint2*)y)[i] = o;
}

// ---------------- tiled transpose-cast: W[K][N] fp32 -> WT[N][K] bf16 ----------------
__global__ void transpose_cast(const float* __restrict__ W, unsigned short* __restrict__ WT,
                               int K, int N) {
  __shared__ float t[64][65];
  int k0 = blockIdx.x * 64, n0 = blockIdx.y * 64;
  int tn = threadIdx.x & 63, tk = threadIdx.x >> 6;
#pragma unroll
  for (int i = 0; i < 64; i += 4)
    t[tk + i][tn] = W[(size_t)(k0 + tk + i) * N + n0 + tn];
  __syncthreads();
  int k2 = (threadIdx.x & 31) * 2, n = threadIdx.x >> 5;
#pragma unroll
  for (int i = 0; i < 64; i += 8) {
    int nn = n + i;
    unsigned o = (unsigned)f32_bf16(t[k2][nn]) | ((unsigned)f32_bf16(t[k2 + 1][nn]) << 16);
    *(unsigned*)&WT[(size_t)(n0 + nn) * K + k0 + k2] = o;
  }
}

// ---------------- mask uniformity check ----------------
__global__ void mask_check(const float* __restrict__ m, int* __restrict__ flag) {
  size_t i = ((size_t)blockIdx.x * 256 + threadIdx.x) * 4;
  float4 v = *(const float4*)(m + i);
  if (v.x != 1.0f || v.y != 1.0f || v.z != 1.0f || v.w != 1.0f) atomicOr(flag, 1);
}

// ---------------- GEMM: C[M][N] = A[M][K] * BT[N][K]^T ----------------
// MODE 0: fp32 C. MODE 2: scatter Qb/Kb [b,h,s,d], VTb [b,h,d,s] (TN must be 128).
// VTb s-index is permuted within each 128-block: f(k)=p*32+q4*8+half*4+j so the attn
// kernel can read PV B-fragments (two 16x16x16 tiles) with a single b128.
// Double-buffered one-barrier K-loop (attn-style): tile kt+1 is staged into the
// alternate buffer right AFTER the barrier, so its loads have the whole compute
// phase of tile kt to land before the next barrier's vmcnt(0) drain. The previous
// single-buffer form (issue loads -> barrier -> compute) paid a full load latency
// every K-step with only 2-3 blocks/CU of implicit overlap (latency-bound regime).
template <int MODE, int TN>
__global__ void __launch_bounds__(256) gemm_bt(const unsigned short* __restrict__ A,
                                               const unsigned short* __restrict__ BT,
                                               float* __restrict__ Cout,
                                               unsigned short* __restrict__ Qb,
                                               unsigned short* __restrict__ Kb,
                                               unsigned short* __restrict__ VTb,
                                               int M, int N, int K) {
  constexpr int NT = TN / 32;
  __shared__ __align__(16) unsigned short As[2][128 * 32];
  __shared__ __align__(16) unsigned short Bs[2][TN * 32];
  const int tid = threadIdx.x, wave = tid >> 6, lane = tid & 63;
  const int l = lane & 15, quad = lane >> 4;
  const int wm = (wave & 1) * 64, wn = (wave >> 1) * (TN >> 1);
  const int bm = blockIdx.x, bn = blockIdx.y;

  const int srowA = wave * 32 + (lane >> 2);
  const int sswzA = ((lane & 3) ^ (srowA & 3)) * 8;
  const int srowB = (TN == 128) ? srowA : (wave * 16 + (lane >> 2));
  const int sswzB = ((lane & 3) ^ (srowB & 3)) * 8;
  const unsigned short* pA = A + (size_t)(bm * 128 + srowA) * K + sswzA;
  const unsigned short* pB = BT + (size_t)(bn * TN + srowB) * K + sswzB;
  const int ldsA0 = (wave * 32) * 32;
  const int ldsA1 = (wave * 32 + 16) * 32;
  const int ldsB0 = (TN == 128 ? wave * 32 : wave * 16) * 32;
  const int ldsB1 = (wave * 32 + 16) * 32;  // TN==128 only

  auto stage = [&](int buf) {
    gload16(pA, &As[buf][ldsA0]);
    gload16(pA + (size_t)16 * K, &As[buf][ldsA1]);
    gload16(pB, &Bs[buf][ldsB0]);
    if (TN == 128) gload16(pB + (size_t)16 * K, &Bs[buf][ldsB1]);
    pA += 32; pB += 32;
  };

  f32x4 acc[4][NT];
#pragma unroll
  for (int i = 0; i < 4; i++)
#pragma unroll
    for (int j = 0; j < NT; j++) { f32x4 z = {0.f, 0.f, 0.f, 0.f}; acc[i][j] = z; }

  // prologue: stage tile 0 into buf 0
  stage(0);

  const int nkt = K >> 5;
  for (int kt = 0; kt < nkt; kt++) {
    const int cur = kt & 1;
    __syncthreads();  // drains buf[cur] staging; all reads of buf[cur^1] finished
    if (kt + 1 < nkt) stage(cur ^ 1);  // lands during this tile's compute
    bf16x8 af[4], bv[NT];
#pragma unroll
    for (int mt = 0; mt < 4; mt++) {
      int r = wm + mt * 16 + l;
      af[mt] = *(const bf16x8*)&As[cur][r * 32 + ((quad ^ (r & 3)) * 8)];
    }
#pragma unroll
    for (int nt = 0; nt < NT; nt++) {
      int r = wn + nt * 16 + l;
      bv[nt] = *(const bf16x8*)&Bs[cur][r * 32 + ((quad ^ (r & 3)) * 8)];
    }
#pragma unroll
    for (int mt = 0; mt < 4; mt++)
#pragma unroll
      for (int nt = 0; nt < NT; nt++)
        acc[mt][nt] = __builtin_amdgcn_mfma_f32_16x16x32_bf16(af[mt], bv[nt], acc[mt][nt], 0, 0, 0);
  }

  // epilogue: C/D layout col = lane&15, row = quad*4 + r
#pragma unroll
  for (int nt = 0; nt < NT; nt++) {
    const int col = bn * TN + wn + nt * 16 + l;
#pragma unroll
    for (int mt = 0; mt < 4; mt++) {
      const int row0 = bm * 128 + wm + mt * 16 + quad * 4;
      if (MODE == 0) {
#pragma unroll
        for (int r = 0; r < 4; r++)
          Cout[(size_t)(row0 + r) * N + col] = acc[mt][nt][r];
      } else {
        const int bb = row0 >> 11, s = row0 & 2047;
        if (col < 2048) {
          unsigned short* dst = (col < 1024) ? Qb : Kb;
          const int c = col & 1023;
          const size_t off = ((size_t)(bb * 16 + (c >> 6)) * 2048 + s) * 64 + (c & 63);
#pragma unroll
          for (int r = 0; r < 4; r++)
            dst[off + (size_t)r * 64] = f32_bf16(acc[mt][nt][r]);
        } else {
          const int c = col - 2048;
          // permute s within its 128-block: keep bits 6,5,1,0; bits 3,2 -> 4,3; bit 4 -> 2
          const int sl = s & 127;
          const int snew = (s & ~127) | (sl & 0x63) | ((sl & 0x0C) << 1) | ((sl & 0x10) >> 2);
          const size_t off = ((size_t)(bb * 16 + (c >> 6)) * 64 + (c & 63)) * 2048 + snew;
          bf16x4 pk;
#pragma unroll
          for (int r = 0; r < 4; r++) pk[r] = (__bf16)acc[mt][nt][r];
          *(bf16x4*)&VTb[off] = pk;
        }
      }
    }
  }
}

// ---------------- fused flash attention, S^T form, P-in-registers, double-buffered ----------------
// grid 512 = 16 q-tiles x 32 (b,h); block 512 = 8 waves = 4 wq (32 q-rows) x 2 wk (64 k-rows).
// The k-split halves per-wave LDS reads (K: 8 b128, V: 8 b128 per kt) vs the q-only split;
// wk halves combine O/l once at the end through the freed KV buffer.
// QK and PV are interleaved per ntk-PAIR so only pa[2][2] (8 VGPRs) is live at a time:
// the pa[2][4] variant exceeded the 64-arch-VGPR budget (Oa/s take the AGPR side of the
// unified file under __launch_bounds__(512,4)) and spilled ~64B/thread to scratch
// (measured: +16MB HBM WRITE_SIZE, MfmaUtil 32->27).
// blockIdx decode puts all 16 q-blocks of one (b,h) on the same XCD (bid%8 round-robin).
// One barrier per K-iteration: tile kt+2 is staged into the buffer consumed at iter kt.
__global__ void __launch_bounds__(512, 4) attn(const unsigned short* __restrict__ Qb,
                                               const unsigned short* __restrict__ Kb,
                                               const unsigned short* __restrict__ VTb,
                                               const float* __restrict__ mask,
                                               const float* __restrict__ emb,
                                               const int* __restrict__ mflag,
                                               unsigned short* __restrict__ ctx) {
  // two buffers, each: K tile (128x64) + V^T tile (64x128)
  __shared__ __align__(16) unsigned short KV[2][16384];
  __shared__ float biasLUT[512];

  const float LOG2E = 1.4426950408889634f;
  const float c1 = 0.125f * LOG2E;
  const float C2 = 10000.0f * LOG2E;
  const int tid = threadIdx.x, wave = tid >> 6, lane = tid & 63;
  const int l = lane & 15, quad = lane >> 4;
  const int wq = wave & 3, wk = wave >> 2;
  const int bh = blockIdx.x & 31, qt = blockIdx.x >> 5;
  const int b = bh >> 4, h = bh & 15;
  const int q0 = qt * 128;

  {
    int i = tid;  // 512 threads cover the 512-entry LUT exactly once
    int rel = i - 256;
    int rp = rel < 0 ? -rel : rel;
    int off = rp < 8 ? rp
                     : 8 + (rp >= 12) + (rp >= 16) + (rp >= 23) + (rp >= 32) +
                           (rp >= 46) + (rp >= 64) + (rp >= 91);
    int bucket = (rel > 0 ? 16 : 0) + off;
    biasLUT[i] = emb[bucket * 16 + h] * LOG2E;
  }
  const float satL = emb[15 * 16 + h] * LOG2E;
  const float satH = emb[31 * 16 + h] * LOG2E;
  const int masked = *mflag;

  const unsigned short* qb  = Qb  + ((size_t)(b * 16 + h) * 2048 + q0) * 64;
  const unsigned short* kb  = Kb  + (size_t)(b * 16 + h) * 2048 * 64;
  const unsigned short* vtb = VTb + (size_t)(b * 16 + h) * 64 * 2048;
  const float* mbase = mask + (size_t)b * 2048 * 2048;

  const int rw8 = lane >> 3, c8s = lane & 7;    // K/Q staging: 8 chunks/row
  const int rw16 = lane >> 4, c16 = lane & 15;  // V staging: 16 chunks/row

  // ---- prologue: Q -> buf1 K-region, tile0 K/V -> buf0 ----
#pragma unroll
  for (int j = 0; j < 2; j++) {
    int row = wave * 16 + j * 8 + rw8;
    gload16(qb + (size_t)row * 64 + ((c8s ^ (row & 7)) * 8), &KV[1][(wave * 16 + j * 8) * 64]);
  }
#pragma unroll
  for (int j = 0; j < 2; j++) {
    int row = wave * 16 + j * 8 + rw8;
    gload16(kb + (size_t)row * 64 + ((c8s ^ (row & 7)) * 8), &KV[0][(wave * 16 + j * 8) * 64]);
  }
#pragma unroll
  for (int j = 0; j < 2; j++) {
    int drow = wave * 8 + j * 4 + rw16;
    gload16(vtb + (size_t)drow * 2048 + ((c16 ^ (drow & 7)) * 8),
            &KV[0][8192 + (wave * 8 + j * 4) * 128]);
  }
  __syncthreads();

  // each wave reads its 32 Q rows (staged region of buf1)
  bf16x8 qf[2][2];
#pragma unroll
  for (int mtq = 0; mtq < 2; mtq++)
#pragma unroll
    for (int ks = 0; ks < 2; ks++) {
      int row = wq * 32 + mtq * 16 + l;
      qf[mtq][ks] = *(const bf16x8*)&KV[1][row * 64 + (((ks * 4 + quad) ^ (row & 7)) * 8)];
    }
  __syncthreads();  // Q reads complete before buf1 is overwritten with tile1

  // ---- stage tile1 -> buf1 ----
#pragma unroll
  for (int j = 0; j < 2; j++) {
    int row = wave * 16 + j * 8 + rw8;
    gload16(kb + (size_t)(128 + row) * 64 + ((c8s ^ (row & 7)) * 8),
            &KV[1][(wave * 16 + j * 8) * 64]);
  }
#pragma unroll
  for (int j = 0; j < 2; j++) {
    int drow = wave * 8 + j * 4 + rw16;
    gload16(vtb + (size_t)drow * 2048 + 128 + ((c16 ^ (drow & 7)) * 8),
            &KV[1][8192 + (wave * 8 + j * 4) * 128]);
  }

  float lr[2] = {0.f, 0.f};
  f32x4 Oa[2][4];
#pragma unroll
  for (int mtq = 0; mtq < 2; mtq++)
#pragma unroll
    for (int dt = 0; dt < 4; dt++) { f32x4 z = {0.f, 0.f, 0.f, 0.f}; Oa[mtq][dt] = z; }

  for (int kt = 0; kt < 16; kt++) {
    const int k0 = kt * 128;
    const unsigned short* Ks  = KV[kt & 1];
    const unsigned short* VTs = KV[kt & 1] + 8192;

    const int d0 = k0 - q0;
    const bool sat = (d0 >= 256) || (d0 <= -256);
    const float bias_u = d0 > 0 ? satH : satL;
    const int ibase = 256 + d0 + wk * 64 + quad * 4 - wq * 32 - l;

    // ---- interleaved per ntk-pair: S^T (2 k-slabs) then PV for those slabs ----
#pragma unroll
    for (int p = 0; p < 2; p++) {
      bf16x4 pa[2][2];
#pragma unroll
      for (int t = 0; t < 2; t++) {
        const int ntk = p * 2 + t;
        int row = wk * 64 + ntk * 16 + l;
        bf16x8 kf0 = *(const bf16x8*)&Ks[row * 64 + ((quad ^ (row & 7)) * 8)];
        bf16x8 kf1 = *(const bf16x8*)&Ks[row * 64 + (((4 + quad) ^ (row & 7)) * 8)];
#pragma unroll
        for (int mtq = 0; mtq < 2; mtq++) {
          f32x4 s = {0.f, 0.f, 0.f, 0.f};
          s = __builtin_amdgcn_mfma_f32_16x16x32_bf16(kf0, qf[mtq][0], s, 0, 0, 0);
          s = __builtin_amdgcn_mfma_f32_16x16x32_bf16(kf1, qf[mtq][1], s, 0, 0, 0);

          const int ib = ibase + ntk * 16 - mtq * 16;
          if (!masked) {
            if (sat) {
#pragma unroll
              for (int r = 0; r < 4; r++) s[r] = fmaf(s[r], c1, bias_u);
            } else {
#pragma unroll
              for (int r = 0; r < 4; r++) s[r] = fmaf(s[r], c1, biasLUT[ib + r]);
            }
          } else {
            const int qg = q0 + wq * 32 + mtq * 16 + l;
            const int kg = k0 + wk * 64 + ntk * 16 + quad * 4;
            float4 mv4 = *(const float4*)&mbase[(size_t)qg * 2048 + kg];
#pragma unroll
            for (int r = 0; r < 4; r++) {
              float mv = r == 0 ? mv4.x : (r == 1 ? mv4.y : (r == 2 ? mv4.z : mv4.w));
              float bias = sat ? bias_u : biasLUT[ib + r];
              s[r] = fmaf(s[r], mv * c1, fmaf(mv, C2, bias - C2));
            }
          }
          bf16x4 pk;
          float ls = 0.f;
#pragma unroll
          for (int r = 0; r < 4; r++) {
            float pv = __builtin_amdgcn_exp2f(s[r]);  // softmax shift-invariance: no max needed
            ls += pv;
            pk[r] = (__bf16)pv;
          }
          lr[mtq] += ls;
          pa[mtq][t] = pk;
        }
      }

      // ---- O += P V for this pair; one b128 per dt covers both k-slabs ----
#pragma unroll
      for (int dt = 0; dt < 4; dt++) {
        int row = dt * 16 + l;
        bf16x8 w = *(const bf16x8*)&VTs[row * 128 + (((wk * 8 + p * 4 + quad) ^ (l & 7)) * 8)];
        bf16x4 vlo = __builtin_shufflevector(w, w, 0, 1, 2, 3);
        bf16x4 vhi = __builtin_shufflevector(w, w, 4, 5, 6, 7);
#pragma unroll
        for (int mtq = 0; mtq < 2; mtq++) {
          Oa[mtq][dt] = mfma16_bf16(pa[mtq][0], vlo, Oa[mtq][dt]);
          Oa[mtq][dt] = mfma16_bf16(pa[mtq][1], vhi, Oa[mtq][dt]);
        }
      }
    }

    // ---- one barrier: all reads of this buffer done + next tile's loads landed ----
    __syncthreads();
    if (kt + 2 < 16) {
      const int kn = (kt + 2) * 128;
      unsigned short* dst = (unsigned short*)KV[kt & 1];
#pragma unroll
      for (int j = 0; j < 2; j++) {
        int row = wave * 16 + j * 8 + rw8;
        gload16(kb + (size_t)(kn + row) * 64 + ((c8s ^ (row & 7)) * 8),
                &dst[(wave * 16 + j * 8) * 64]);
      }
#pragma unroll
      for (int j = 0; j < 2; j++) {
        int drow = wave * 8 + j * 4 + rw16;
        gload16(vtb + (size_t)drow * 2048 + kn + ((c16 ^ (drow & 7)) * 8),
                &dst[8192 + (wave * 8 + j * 4) * 128]);
      }
    }
  }

  // ---- cross-wave (wk) reduction through freed KV, then normalize + store ----
  float* Of = (float*)KV;       // 8192 floats = 32KB (q 0..127 x d 0..63)
  float* Lf = Of + 8192;        // 128 floats
  if (wk == 1) {
#pragma unroll
    for (int mtq = 0; mtq < 2; mtq++) {
      float v = lr[mtq];
      v += __shfl_xor(v, 16);
      v += __shfl_xor(v, 32);
      if (quad == 0) Lf[wq * 32 + mtq * 16 + l] = v;
#pragma unroll
      for (int dt = 0; dt < 4; dt++)
#pragma unroll
        for (int r = 0; r < 4; r++)
          Of[(wq * 32 + mtq * 16 + quad * 4 + r) * 64 + dt * 16 + l] = Oa[mtq][dt][r];
    }
  }
  __syncthreads();
  if (wk == 0) {
#pragma unroll
    for (int mtq = 0; mtq < 2; mtq++) {
      float v = lr[mtq];
      v += __shfl_xor(v, 16);
      v += __shfl_xor(v, 32);
      v += Lf[wq * 32 + mtq * 16 + l];
      const float inv = 1.0f / v;
#pragma unroll
      for (int r = 0; r < 4; r++) {
        float i_bc = bcast_lane(inv, quad * 4 + r);
        const int qg = q0 + wq * 32 + mtq * 16 + quad * 4 + r;
#pragma unroll
        for (int dt = 0; dt < 4; dt++) {
          float o = Oa[mtq][dt][r] +
                    Of[(wq * 32 + mtq * 16 + quad * 4 + r) * 64 + dt * 16 + l];
          ctx[(size_t)(b * 2048 + qg) * 1024 + h * 64 + dt * 16 + l] = f32_bf16(o * i_bc);
        }
      }
    }
  }
}

// ---------------- launch ----------------
extern "C" void kernel_launch(void* const* d_in, const int* in_sizes, int n_in,
                              void* d_out, int out_size, void* d_ws, size_t ws_size,
                              hipStream_t stream) {
  const float* hs   = (const float*)d_in[0];
  const float* mask = (const float*)d_in[1];
  const float* wqkv = (const float*)d_in[2];
  const float* wo   = (const float*)d_in[3];
  const float* emb  = (const float*)d_in[4];
  float* out = (float*)d_out;

  char* ws = (char*)d_ws;
  unsigned short* hB  = (unsigned short*)(ws);               //  8 MB (alias ctx)
  unsigned short* ctx = (unsigned short*)(ws);               //  alias
  unsigned short* wqT = (unsigned short*)(ws + 8388608);     //  6 MB
  unsigned short* woT = (unsigned short*)(ws + 14680064);    //  2 MB
  unsigned short* Qb  = (unsigned short*)(ws + 16777216);    //  8 MB  [b,h,s,d]
  unsigned short* Kb  = (unsigned short*)(ws + 25165824);    //  8 MB  [b,h,s,d]
  unsigned short* VTb = (unsigned short*)(ws + 33554432);    //  8 MB  [b,h,d,s] (s-permuted)
  int* mflag          = (int*)(ws + 41943040);
  if (ws_size < 41943044) return;

  hipMemsetAsync(mflag, 0, 4, stream);
  cast_bf16<<<4096, 256, 0, stream>>>(hs, hB);
  transpose_cast<<<dim3(16, 48), 256, 0, stream>>>(wqkv, wqT, 1024, 3072);
  transpose_cast<<<dim3(16, 16), 256, 0, stream>>>(wo, woT, 1024, 1024);
  mask_check<<<8192, 256, 0, stream>>>(mask, mflag);
  gemm_bt<2, 128><<<dim3(32, 24), 256, 0, stream>>>(hB, wqT, nullptr, Qb, Kb, VTb, 4096, 3072, 1024);
  attn<<<512, 512, 0, stream>>>(Qb, Kb, VTb, mask, emb, mflag, ctx);
  gemm_bt<0, 64><<<dim3(32, 16), 256, 0, stream>>>(ctx, woT, out, nullptr, nullptr, nullptr, 4096, 1024, 1024);
}

// Round 6
// 205.429 us; speedup vs baseline: 1.1376x; 1.0514x over previous
//
#include <hip/hip_runtime.h>
#include <cstdint>

#define DEV static __device__ __forceinline__

typedef __bf16 bf16x8 __attribute__((ext_vector_type(8)));
typedef __bf16 bf16x4 __attribute__((ext_vector_type(4)));
typedef short  s16x4  __attribute__((ext_vector_type(4)));
typedef float  f32x4  __attribute__((ext_vector_type(4)));

DEV unsigned short f32_bf16(float f) {
  union { float f; unsigned u; } v; v.f = f;
  unsigned r = v.u + 0x7FFFu + ((v.u >> 16) & 1u);
  return (unsigned short)(r >> 16);
}

DEV void gload16(const void* g, void* lds) {
  __builtin_amdgcn_global_load_lds((__attribute__((address_space(1))) void*)g,
                                   (__attribute__((address_space(3))) void*)lds,
                                   16, 0, 0);
}

DEV float bcast_lane(float v, int srclane) {
  union { float f; int i; } u; u.f = v;
  u.i = __builtin_amdgcn_ds_bpermute(srclane << 2, u.i);
  return u.f;
}

// ---------------- elementwise cast fp32 -> bf16 ----------------
__global__ void cast_bf16(const float* __restrict__ x, unsigned short* __restrict__ y) {
  int i = blockIdx.x * 256 + threadIdx.x;
  float4 v = ((const float4*)x)[i];
  uint2 o;
  o.x = (unsigned)f32_bf16(v.x) | ((unsigned)f32_bf16(v.y) << 16);
  o.y = (unsigned)f32_bf16(v.z) | ((unsigned)f32_bf16(v.w) << 16);
  ((uint2*)y)[i] = o;
}

// ---------------- tiled transpose-cast: W[K][N] fp32 -> WT[N][K] bf16 ----------------
__global__ void transpose_cast(const float* __restrict__ W, unsigned short* __restrict__ WT,
                               int K, int N) {
  __shared__ float t[64][65];
  int k0 = blockIdx.x * 64, n0 = blockIdx.y * 64;
  int tn = threadIdx.x & 63, tk = threadIdx.x >> 6;
#pragma unroll
  for (int i = 0; i < 64; i += 4)
    t[tk + i][tn] = W[(size_t)(k0 + tk + i) * N + n0 + tn];
  __syncthreads();
  int k2 = (threadIdx.x & 31) * 2, n = threadIdx.x >> 5;
#pragma unroll
  for (int i = 0; i < 64; i += 8) {
    int nn = n + i;
    unsigned o = (unsigned)f32_bf16(t[k2][nn]) | ((unsigned)f32_bf16(t[k2 + 1][nn]) << 16);
    *(unsigned*)&WT[(size_t)(n0 + nn) * K + k0 + k2] = o;
  }
}

// ---------------- mask uniformity check ----------------
__global__ void mask_check(const float* __restrict__ m, int* __restrict__ flag) {
  size_t i = ((size_t)blockIdx.x * 256 + threadIdx.x) * 4;
  float4 v = *(const float4*)(m + i);
  if (v.x != 1.0f || v.y != 1.0f || v.z != 1.0f || v.w != 1.0f) atomicOr(flag, 1);
}

// ---------------- GEMM: C[M][N] = A[M][K] * BT[N][K]^T ----------------
// MODE 0: fp32 C. MODE 2: scatter Qb/Kb [b,h,s,d], VTb [b,h,d,s] (TN must be 128).
// VTb s-index is permuted within each 128-block (keep bits 6,5,1,0; 3,2->4,3; 4->2) so the
// attn PV step can feed one b128 V read directly as the B-operand of a 16x16x32 MFMA
// whose A-operand is the concat of two consecutive QK C-fragments (k-relabeling is
// consistent on both operands, so the contraction is unchanged).
// Double-buffered one-barrier K-loop (attn-style): tile kt+1 is staged into the
// alternate buffer right AFTER the barrier, so its loads have the whole compute
// phase of tile kt to land before the next barrier's vmcnt(0) drain.
template <int MODE, int TN>
__global__ void __launch_bounds__(256) gemm_bt(const unsigned short* __restrict__ A,
                                               const unsigned short* __restrict__ BT,
                                               float* __restrict__ Cout,
                                               unsigned short* __restrict__ Qb,
                                               unsigned short* __restrict__ Kb,
                                               unsigned short* __restrict__ VTb,
                                               int M, int N, int K) {
  constexpr int NT = TN / 32;
  __shared__ __align__(16) unsigned short As[2][128 * 32];
  __shared__ __align__(16) unsigned short Bs[2][TN * 32];
  const int tid = threadIdx.x, wave = tid >> 6, lane = tid & 63;
  const int l = lane & 15, quad = lane >> 4;
  const int wm = (wave & 1) * 64, wn = (wave >> 1) * (TN >> 1);
  const int bm = blockIdx.x, bn = blockIdx.y;

  const int srowA = wave * 32 + (lane >> 2);
  const int sswzA = ((lane & 3) ^ (srowA & 3)) * 8;
  const int srowB = (TN == 128) ? srowA : (wave * 16 + (lane >> 2));
  const int sswzB = ((lane & 3) ^ (srowB & 3)) * 8;
  const unsigned short* pA = A + (size_t)(bm * 128 + srowA) * K + sswzA;
  const unsigned short* pB = BT + (size_t)(bn * TN + srowB) * K + sswzB;
  const int ldsA0 = (wave * 32) * 32;
  const int ldsA1 = (wave * 32 + 16) * 32;
  const int ldsB0 = (TN == 128 ? wave * 32 : wave * 16) * 32;
  const int ldsB1 = (wave * 32 + 16) * 32;  // TN==128 only

  auto stage = [&](int buf) {
    gload16(pA, &As[buf][ldsA0]);
    gload16(pA + (size_t)16 * K, &As[buf][ldsA1]);
    gload16(pB, &Bs[buf][ldsB0]);
    if (TN == 128) gload16(pB + (size_t)16 * K, &Bs[buf][ldsB1]);
    pA += 32; pB += 32;
  };

  f32x4 acc[4][NT];
#pragma unroll
  for (int i = 0; i < 4; i++)
#pragma unroll
    for (int j = 0; j < NT; j++) { f32x4 z = {0.f, 0.f, 0.f, 0.f}; acc[i][j] = z; }

  // prologue: stage tile 0 into buf 0
  stage(0);

  const int nkt = K >> 5;
  for (int kt = 0; kt < nkt; kt++) {
    const int cur = kt & 1;
    __syncthreads();  // drains buf[cur] staging; all reads of buf[cur^1] finished
    if (kt + 1 < nkt) stage(cur ^ 1);  // lands during this tile's compute
    bf16x8 af[4], bv[NT];
#pragma unroll
    for (int mt = 0; mt < 4; mt++) {
      int r = wm + mt * 16 + l;
      af[mt] = *(const bf16x8*)&As[cur][r * 32 + ((quad ^ (r & 3)) * 8)];
    }
#pragma unroll
    for (int nt = 0; nt < NT; nt++) {
      int r = wn + nt * 16 + l;
      bv[nt] = *(const bf16x8*)&Bs[cur][r * 32 + ((quad ^ (r & 3)) * 8)];
    }
#pragma unroll
    for (int mt = 0; mt < 4; mt++)
#pragma unroll
      for (int nt = 0; nt < NT; nt++)
        acc[mt][nt] = __builtin_amdgcn_mfma_f32_16x16x32_bf16(af[mt], bv[nt], acc[mt][nt], 0, 0, 0);
  }

  // epilogue: C/D layout col = lane&15, row = quad*4 + r
#pragma unroll
  for (int nt = 0; nt < NT; nt++) {
    const int col = bn * TN + wn + nt * 16 + l;
#pragma unroll
    for (int mt = 0; mt < 4; mt++) {
      const int row0 = bm * 128 + wm + mt * 16 + quad * 4;
      if (MODE == 0) {
#pragma unroll
        for (int r = 0; r < 4; r++)
          Cout[(size_t)(row0 + r) * N + col] = acc[mt][nt][r];
      } else {
        const int bb = row0 >> 11, s = row0 & 2047;
        if (col < 2048) {
          unsigned short* dst = (col < 1024) ? Qb : Kb;
          const int c = col & 1023;
          const size_t off = ((size_t)(bb * 16 + (c >> 6)) * 2048 + s) * 64 + (c & 63);
#pragma unroll
          for (int r = 0; r < 4; r++)
            dst[off + (size_t)r * 64] = f32_bf16(acc[mt][nt][r]);
        } else {
          const int c = col - 2048;
          // permute s within its 128-block: keep bits 6,5,1,0; bits 3,2 -> 4,3; bit 4 -> 2
          const int sl = s & 127;
          const int snew = (s & ~127) | (sl & 0x63) | ((sl & 0x0C) << 1) | ((sl & 0x10) >> 2);
          const size_t off = ((size_t)(bb * 16 + (c >> 6)) * 64 + (c & 63)) * 2048 + snew;
          bf16x4 pk;
#pragma unroll
          for (int r = 0; r < 4; r++) pk[r] = (__bf16)acc[mt][nt][r];
          *(bf16x4*)&VTb[off] = pk;
        }
      }
    }
  }
}

// ---------------- fused flash attention, S^T form, P-in-registers, double-buffered ----------------
// grid 512 = 16 q-tiles x 32 (b,h); block 512 = 8 waves = 4 wq (32 q-rows) x 2 wk (64 k-rows).
// The k-split halves per-wave LDS reads (K: 8 b128, V: 8 b128 per kt) vs the q-only split;
// wk halves combine O/l once at the end through the freed KV buffer.
// PV uses 16x16x32 MFMA: A = concat of the two consecutive QK C-fragments (pa8),
// B = one b128 V read (the VTb s-permutation makes both operands' k-relabeling
// identical: slot quad*8+j <-> phys k = p*32 + (j>=4)*16 + quad*4 + (j&3)).
// This halves PV MFMA instructions vs the 16x16x16 pair form and removes the
// vlo/vhi extraction movs.
// QK and PV stay interleaved per ntk-PAIR so only pa8[2] (8 VGPRs) is live at a time
// (pa[2][4] spilled: measured +16MB HBM WRITE_SIZE).
// blockIdx decode puts all 16 q-blocks of one (b,h) on the same XCD (bid%8 round-robin).
// One barrier per K-iteration: tile kt+2 is staged into the buffer consumed at iter kt.
__global__ void __launch_bounds__(512, 4) attn(const unsigned short* __restrict__ Qb,
                                               const unsigned short* __restrict__ Kb,
                                               const unsigned short* __restrict__ VTb,
                                               const float* __restrict__ mask,
                                               const float* __restrict__ emb,
                                               const int* __restrict__ mflag,
                                               unsigned short* __restrict__ ctx) {
  // two buffers, each: K tile (128x64) + V^T tile (64x128)
  __shared__ __align__(16) unsigned short KV[2][16384];
  __shared__ float biasLUT[512];

  const float LOG2E = 1.4426950408889634f;
  const float c1 = 0.125f * LOG2E;
  const float C2 = 10000.0f * LOG2E;
  const int tid = threadIdx.x, wave = tid >> 6, lane = tid & 63;
  const int l = lane & 15, quad = lane >> 4;
  const int wq = wave & 3, wk = wave >> 2;
  const int bh = blockIdx.x & 31, qt = blockIdx.x >> 5;
  const int b = bh >> 4, h = bh & 15;
  const int q0 = qt * 128;

  {
    int i = tid;  // 512 threads cover the 512-entry LUT exactly once
    int rel = i - 256;
    int rp = rel < 0 ? -rel : rel;
    int off = rp < 8 ? rp
                     : 8 + (rp >= 12) + (rp >= 16) + (rp >= 23) + (rp >= 32) +
                           (rp >= 46) + (rp >= 64) + (rp >= 91);
    int bucket = (rel > 0 ? 16 : 0) + off;
    biasLUT[i] = emb[bucket * 16 + h] * LOG2E;
  }
  const float satL = emb[15 * 16 + h] * LOG2E;
  const float satH = emb[31 * 16 + h] * LOG2E;
  const int masked = *mflag;

  const unsigned short* qb  = Qb  + ((size_t)(b * 16 + h) * 2048 + q0) * 64;
  const unsigned short* kb  = Kb  + (size_t)(b * 16 + h) * 2048 * 64;
  const unsigned short* vtb = VTb + (size_t)(b * 16 + h) * 64 * 2048;
  const float* mbase = mask + (size_t)b * 2048 * 2048;

  const int rw8 = lane >> 3, c8s = lane & 7;    // K/Q staging: 8 chunks/row
  const int rw16 = lane >> 4, c16 = lane & 15;  // V staging: 16 chunks/row

  // ---- prologue: Q -> buf1 K-region, tile0 K/V -> buf0 ----
#pragma unroll
  for (int j = 0; j < 2; j++) {
    int row = wave * 16 + j * 8 + rw8;
    gload16(qb + (size_t)row * 64 + ((c8s ^ (row & 7)) * 8), &KV[1][(wave * 16 + j * 8) * 64]);
  }
#pragma unroll
  for (int j = 0; j < 2; j++) {
    int row = wave * 16 + j * 8 + rw8;
    gload16(kb + (size_t)row * 64 + ((c8s ^ (row & 7)) * 8), &KV[0][(wave * 16 + j * 8) * 64]);
  }
#pragma unroll
  for (int j = 0; j < 2; j++) {
    int drow = wave * 8 + j * 4 + rw16;
    gload16(vtb + (size_t)drow * 2048 + ((c16 ^ (drow & 7)) * 8),
            &KV[0][8192 + (wave * 8 + j * 4) * 128]);
  }
  __syncthreads();

  // each wave reads its 32 Q rows (staged region of buf1)
  bf16x8 qf[2][2];
#pragma unroll
  for (int mtq = 0; mtq < 2; mtq++)
#pragma unroll
    for (int ks = 0; ks < 2; ks++) {
      int row = wq * 32 + mtq * 16 + l;
      qf[mtq][ks] = *(const bf16x8*)&KV[1][row * 64 + (((ks * 4 + quad) ^ (row & 7)) * 8)];
    }
  __syncthreads();  // Q reads complete before buf1 is overwritten with tile1

  // ---- stage tile1 -> buf1 ----
#pragma unroll
  for (int j = 0; j < 2; j++) {
    int row = wave * 16 + j * 8 + rw8;
    gload16(kb + (size_t)(128 + row) * 64 + ((c8s ^ (row & 7)) * 8),
            &KV[1][(wave * 16 + j * 8) * 64]);
  }
#pragma unroll
  for (int j = 0; j < 2; j++) {
    int drow = wave * 8 + j * 4 + rw16;
    gload16(vtb + (size_t)drow * 2048 + 128 + ((c16 ^ (drow & 7)) * 8),
            &KV[1][8192 + (wave * 8 + j * 4) * 128]);
  }

  float lr[2] = {0.f, 0.f};
  f32x4 Oa[2][4];
#pragma unroll
  for (int mtq = 0; mtq < 2; mtq++)
#pragma unroll
    for (int dt = 0; dt < 4; dt++) { f32x4 z = {0.f, 0.f, 0.f, 0.f}; Oa[mtq][dt] = z; }

  for (int kt = 0; kt < 16; kt++) {
    const int k0 = kt * 128;
    const unsigned short* Ks  = KV[kt & 1];
    const unsigned short* VTs = KV[kt & 1] + 8192;

    const int d0 = k0 - q0;
    const bool sat = (d0 >= 256) || (d0 <= -256);
    const float bias_u = d0 > 0 ? satH : satL;
    const int ibase = 256 + d0 + wk * 64 + quad * 4 - wq * 32 - l;

    // ---- interleaved per ntk-pair: S^T (2 k-slabs) then PV for those slabs ----
#pragma unroll
    for (int p = 0; p < 2; p++) {
      bf16x8 pa8[2];  // A-fragment for 16x16x32 PV: slots 0-3 from ntk even, 4-7 odd
#pragma unroll
      for (int t = 0; t < 2; t++) {
        const int ntk = p * 2 + t;
        int row = wk * 64 + ntk * 16 + l;
        bf16x8 kf0 = *(const bf16x8*)&Ks[row * 64 + ((quad ^ (row & 7)) * 8)];
        bf16x8 kf1 = *(const bf16x8*)&Ks[row * 64 + (((4 + quad) ^ (row & 7)) * 8)];
#pragma unroll
        for (int mtq = 0; mtq < 2; mtq++) {
          f32x4 s = {0.f, 0.f, 0.f, 0.f};
          s = __builtin_amdgcn_mfma_f32_16x16x32_bf16(kf0, qf[mtq][0], s, 0, 0, 0);
          s = __builtin_amdgcn_mfma_f32_16x16x32_bf16(kf1, qf[mtq][1], s, 0, 0, 0);

          const int ib = ibase + ntk * 16 - mtq * 16;
          if (!masked) {
            if (sat) {
#pragma unroll
              for (int r = 0; r < 4; r++) s[r] = fmaf(s[r], c1, bias_u);
            } else {
#pragma unroll
              for (int r = 0; r < 4; r++) s[r] = fmaf(s[r], c1, biasLUT[ib + r]);
            }
          } else {
            const int qg = q0 + wq * 32 + mtq * 16 + l;
            const int kg = k0 + wk * 64 + ntk * 16 + quad * 4;
            float4 mv4 = *(const float4*)&mbase[(size_t)qg * 2048 + kg];
#pragma unroll
            for (int r = 0; r < 4; r++) {
              float mv = r == 0 ? mv4.x : (r == 1 ? mv4.y : (r == 2 ? mv4.z : mv4.w));
              float bias = sat ? bias_u : biasLUT[ib + r];
              s[r] = fmaf(s[r], mv * c1, fmaf(mv, C2, bias - C2));
            }
          }
          float ls = 0.f;
#pragma unroll
          for (int r = 0; r < 4; r++) {
            float pv = __builtin_amdgcn_exp2f(s[r]);  // softmax shift-invariance: no max needed
            ls += pv;
            pa8[mtq][t * 4 + r] = (__bf16)pv;
          }
          lr[mtq] += ls;
        }
      }

      // ---- O += P V: one 16x16x32 MFMA per (dt,mtq); B straight from b128 ----
#pragma unroll
      for (int dt = 0; dt < 4; dt++) {
        int row = dt * 16 + l;
        bf16x8 w = *(const bf16x8*)&VTs[row * 128 + (((wk * 8 + p * 4 + quad) ^ (l & 7)) * 8)];
#pragma unroll
        for (int mtq = 0; mtq < 2; mtq++)
          Oa[mtq][dt] = __builtin_amdgcn_mfma_f32_16x16x32_bf16(pa8[mtq], w, Oa[mtq][dt], 0, 0, 0);
      }
    }

    // ---- one barrier: all reads of this buffer done + next tile's loads landed ----
    __syncthreads();
    if (kt + 2 < 16) {
      const int kn = (kt + 2) * 128;
      unsigned short* dst = (unsigned short*)KV[kt & 1];
#pragma unroll
      for (int j = 0; j < 2; j++) {
        int row = wave * 16 + j * 8 + rw8;
        gload16(kb + (size_t)(kn + row) * 64 + ((c8s ^ (row & 7)) * 8),
                &dst[(wave * 16 + j * 8) * 64]);
      }
#pragma unroll
      for (int j = 0; j < 2; j++) {
        int drow = wave * 8 + j * 4 + rw16;
        gload16(vtb + (size_t)drow * 2048 + kn + ((c16 ^ (drow & 7)) * 8),
                &dst[8192 + (wave * 8 + j * 4) * 128]);
      }
    }
  }

  // ---- cross-wave (wk) reduction through freed KV, then normalize + store ----
  float* Of = (float*)KV;       // 8192 floats = 32KB (q 0..127 x d 0..63)
  float* Lf = Of + 8192;        // 128 floats
  if (wk == 1) {
#pragma unroll
    for (int mtq = 0; mtq < 2; mtq++) {
      float v = lr[mtq];
      v += __shfl_xor(v, 16);
      v += __shfl_xor(v, 32);
      if (quad == 0) Lf[wq * 32 + mtq * 16 + l] = v;
#pragma unroll
      for (int dt = 0; dt < 4; dt++)
#pragma unroll
        for (int r = 0; r < 4; r++)
          Of[(wq * 32 + mtq * 16 + quad * 4 + r) * 64 + dt * 16 + l] = Oa[mtq][dt][r];
    }
  }
  __syncthreads();
  if (wk == 0) {
#pragma unroll
    for (int mtq = 0; mtq < 2; mtq++) {
      float v = lr[mtq];
      v += __shfl_xor(v, 16);
      v += __shfl_xor(v, 32);
      v += Lf[wq * 32 + mtq * 16 + l];
      const float inv = 1.0f / v;
#pragma unroll
      for (int r = 0; r < 4; r++) {
        float i_bc = bcast_lane(inv, quad * 4 + r);
        const int qg = q0 + wq * 32 + mtq * 16 + quad * 4 + r;
#pragma unroll
        for (int dt = 0; dt < 4; dt++) {
          float o = Oa[mtq][dt][r] +
                    Of[(wq * 32 + mtq * 16 + quad * 4 + r) * 64 + dt * 16 + l];
          ctx[(size_t)(b * 2048 + qg) * 1024 + h * 64 + dt * 16 + l] = f32_bf16(o * i_bc);
        }
      }
    }
  }
}

// ---------------- launch ----------------
extern "C" void kernel_launch(void* const* d_in, const int* in_sizes, int n_in,
                              void* d_out, int out_size, void* d_ws, size_t ws_size,
                              hipStream_t stream) {
  const float* hs   = (const float*)d_in[0];
  const float* mask = (const float*)d_in[1];
  const float* wqkv = (const float*)d_in[2];
  const float* wo   = (const float*)d_in[3];
  const float* emb  = (const float*)d_in[4];
  float* out = (float*)d_out;

  char* ws = (char*)d_ws;
  unsigned short* hB  = (unsigned short*)(ws);               //  8 MB (alias ctx)
  unsigned short* ctx = (unsigned short*)(ws);               //  alias
  unsigned short* wqT = (unsigned short*)(ws + 8388608);     //  6 MB
  unsigned short* woT = (unsigned short*)(ws + 14680064);    //  2 MB
  unsigned short* Qb  = (unsigned short*)(ws + 16777216);    //  8 MB  [b,h,s,d]
  unsigned short* Kb  = (unsigned short*)(ws + 25165824);    //  8 MB  [b,h,s,d]
  unsigned short* VTb = (unsigned short*)(ws + 33554432);    //  8 MB  [b,h,d,s] (s-permuted)
  int* mflag          = (int*)(ws + 41943040);
  if (ws_size < 41943044) return;

  hipMemsetAsync(mflag, 0, 4, stream);
  cast_bf16<<<4096, 256, 0, stream>>>(hs, hB);
  transpose_cast<<<dim3(16, 48), 256, 0, stream>>>(wqkv, wqT, 1024, 3072);
  transpose_cast<<<dim3(16, 16), 256, 0, stream>>>(wo, woT, 1024, 1024);
  mask_check<<<8192, 256, 0, stream>>>(mask, mflag);
  gemm_bt<2, 128><<<dim3(32, 24), 256, 0, stream>>>(hB, wqT, nullptr, Qb, Kb, VTb, 4096, 3072, 1024);
  attn<<<512, 512, 0, stream>>>(Qb, Kb, VTb, mask, emb, mflag, ctx);
  gemm_bt<0, 64><<<dim3(32, 16), 256, 0, stream>>>(ctx, woT, out, nullptr, nullptr, nullptr, 4096, 1024, 1024);
}

// Round 7
// 205.087 us; speedup vs baseline: 1.1395x; 1.0017x over previous
//
#include <hip/hip_runtime.h>
#include <cstdint>

#define DEV static __device__ __forceinline__

typedef __bf16 bf16x8 __attribute__((ext_vector_type(8)));
typedef __bf16 bf16x4 __attribute__((ext_vector_type(4)));
typedef short  s16x4  __attribute__((ext_vector_type(4)));
typedef float  f32x4  __attribute__((ext_vector_type(4)));

#define VM_WAIT4 asm volatile("s_waitcnt vmcnt(4)" ::: "memory")
#define VM_WAIT3 asm volatile("s_waitcnt vmcnt(3)" ::: "memory")
#define VM_WAIT0 asm volatile("s_waitcnt vmcnt(0)" ::: "memory")

DEV unsigned short f32_bf16(float f) {
  union { float f; unsigned u; } v; v.f = f;
  unsigned r = v.u + 0x7FFFu + ((v.u >> 16) & 1u);
  return (unsigned short)(r >> 16);
}

DEV void gload16(const void* g, void* lds) {
  __builtin_amdgcn_global_load_lds((__attribute__((address_space(1))) void*)g,
                                   (__attribute__((address_space(3))) void*)lds,
                                   16, 0, 0);
}

DEV float bcast_lane(float v, int srclane) {
  union { float f; int i; } u; u.f = v;
  u.i = __builtin_amdgcn_ds_bpermute(srclane << 2, u.i);
  return u.f;
}

// ---------------- elementwise cast fp32 -> bf16 ----------------
__global__ void cast_bf16(const float* __restrict__ x, unsigned short* __restrict__ y) {
  int i = blockIdx.x * 256 + threadIdx.x;
  float4 v = ((const float4*)x)[i];
  uint2 o;
  o.x = (unsigned)f32_bf16(v.x) | ((unsigned)f32_bf16(v.y) << 16);
  o.y = (unsigned)f32_bf16(v.z) | ((unsigned)f32_bf16(v.w) << 16);
  ((uint2*)y)[i] = o;
}

// ---------------- tiled transpose-cast: W[K][N] fp32 -> WT[N][K] bf16 ----------------
__global__ void transpose_cast(const float* __restrict__ W, unsigned short* __restrict__ WT,
                               int K, int N) {
  __shared__ float t[64][65];
  int k0 = blockIdx.x * 64, n0 = blockIdx.y * 64;
  int tn = threadIdx.x & 63, tk = threadIdx.x >> 6;
#pragma unroll
  for (int i = 0; i < 64; i += 4)
    t[tk + i][tn] = W[(size_t)(k0 + tk + i) * N + n0 + tn];
  __syncthreads();
  int k2 = (threadIdx.x & 31) * 2, n = threadIdx.x >> 5;
#pragma unroll
  for (int i = 0; i < 64; i += 8) {
    int nn = n + i;
    unsigned o = (unsigned)f32_bf16(t[k2][nn]) | ((unsigned)f32_bf16(t[k2 + 1][nn]) << 16);
    *(unsigned*)&WT[(size_t)(n0 + nn) * K + k0 + k2] = o;
  }
}

// ---------------- mask uniformity check ----------------
__global__ void mask_check(const float* __restrict__ m, int* __restrict__ flag) {
  size_t i = ((size_t)blockIdx.x * 256 + threadIdx.x) * 4;
  float4 v = *(const float4*)(m + i);
  if (v.x != 1.0f || v.y != 1.0f || v.z != 1.0f || v.w != 1.0f) atomicOr(flag, 1);
}

// ---------------- GEMM: C[M][N] = A[M][K] * BT[N][K]^T ----------------
// MODE 0: fp32 C. MODE 2: scatter Qb/Kb [b,h,s,d], VTb [b,h,d,s] (TN must be 128).
// VTb s-index is permuted within each 128-block (keep bits 6,5,1,0; 3,2->4,3; 4->2) so the
// attn PV step can feed one b128 V read directly as the B-operand of a 16x16x32 MFMA
// whose A-operand is the concat of two consecutive QK C-fragments.
//
// 3-buffer, 2-tiles-ahead pipeline with counted vmcnt + raw s_barrier (T3/T4-lite):
// __syncthreads() would emit s_waitcnt vmcnt(0) before s_barrier, draining the
// prefetch queue and capping latency cover at ONE compute phase. Here each wave
// waits only for its OWN current tile's loads (vmcnt(LOADS) keeps the next tile's
// loads in flight ACROSS the barrier), giving staged loads TWO compute phases to
// land. Safety: each wave stages its own LDS slice, so per-wave vmcnt + barrier
// => buffer complete for all waves; the buffer being restaged ((kt+2)%3 ==
// (kt-1)%3) was consumed into registers before this barrier (ds_read results are
// lgkmcnt-waited before the MFMAs that precede the barrier in program order);
// sched_barrier(0) pins ds_reads/stages from hoisting above the sync point.
template <int MODE, int TN>
__global__ void __launch_bounds__(256) gemm_bt(const unsigned short* __restrict__ A,
                                               const unsigned short* __restrict__ BT,
                                               float* __restrict__ Cout,
                                               unsigned short* __restrict__ Qb,
                                               unsigned short* __restrict__ Kb,
                                               unsigned short* __restrict__ VTb,
                                               int M, int N, int K) {
  constexpr int NT = TN / 32;
  __shared__ __align__(16) unsigned short As[3][128 * 32];
  __shared__ __align__(16) unsigned short Bs[3][TN * 32];
  const int tid = threadIdx.x, wave = tid >> 6, lane = tid & 63;
  const int l = lane & 15, quad = lane >> 4;
  const int wm = (wave & 1) * 64, wn = (wave >> 1) * (TN >> 1);
  const int bm = blockIdx.x, bn = blockIdx.y;

  const int srowA = wave * 32 + (lane >> 2);
  const int sswzA = ((lane & 3) ^ (srowA & 3)) * 8;
  const int srowB = (TN == 128) ? srowA : (wave * 16 + (lane >> 2));
  const int sswzB = ((lane & 3) ^ (srowB & 3)) * 8;
  const unsigned short* pA = A + (size_t)(bm * 128 + srowA) * K + sswzA;
  const unsigned short* pB = BT + (size_t)(bn * TN + srowB) * K + sswzB;
  const int ldsA0 = (wave * 32) * 32;
  const int ldsA1 = (wave * 32 + 16) * 32;
  const int ldsB0 = (TN == 128 ? wave * 32 : wave * 16) * 32;
  const int ldsB1 = (wave * 32 + 16) * 32;  // TN==128 only

  auto stage = [&](int buf) {
    gload16(pA, &As[buf][ldsA0]);
    gload16(pA + (size_t)16 * K, &As[buf][ldsA1]);
    gload16(pB, &Bs[buf][ldsB0]);
    if (TN == 128) gload16(pB + (size_t)16 * K, &Bs[buf][ldsB1]);
    pA += 32; pB += 32;
  };

  f32x4 acc[4][NT];
#pragma unroll
  for (int i = 0; i < 4; i++)
#pragma unroll
    for (int j = 0; j < NT; j++) { f32x4 z = {0.f, 0.f, 0.f, 0.f}; acc[i][j] = z; }

  // prologue: 2 tiles in flight
  stage(0);
  stage(1);

  const int nkt = K >> 5;
  for (int kt = 0; kt < nkt; kt++) {
    const int cur = kt % 3;
    // tile kt's loads (this wave's oldest LOADS) must have landed; tile kt+1's stay in flight
    if (kt != nkt - 1) {
      if (TN == 128) { VM_WAIT4; } else { VM_WAIT3; }
    } else {
      VM_WAIT0;
    }
    __builtin_amdgcn_s_barrier();
    __builtin_amdgcn_sched_barrier(0);
    if (kt + 2 < nkt) stage((kt + 2) % 3);
    bf16x8 af[4], bv[NT];
#pragma unroll
    for (int mt = 0; mt < 4; mt++) {
      int r = wm + mt * 16 + l;
      af[mt] = *(const bf16x8*)&As[cur][r * 32 + ((quad ^ (r & 3)) * 8)];
    }
#pragma unroll
    for (int nt = 0; nt < NT; nt++) {
      int r = wn + nt * 16 + l;
      bv[nt] = *(const bf16x8*)&Bs[cur][r * 32 + ((quad ^ (r & 3)) * 8)];
    }
#pragma unroll
    for (int mt = 0; mt < 4; mt++)
#pragma unroll
      for (int nt = 0; nt < NT; nt++)
        acc[mt][nt] = __builtin_amdgcn_mfma_f32_16x16x32_bf16(af[mt], bv[nt], acc[mt][nt], 0, 0, 0);
  }

  // epilogue: C/D layout col = lane&15, row = quad*4 + r
#pragma unroll
  for (int nt = 0; nt < NT; nt++) {
    const int col = bn * TN + wn + nt * 16 + l;
#pragma unroll
    for (int mt = 0; mt < 4; mt++) {
      const int row0 = bm * 128 + wm + mt * 16 + quad * 4;
      if (MODE == 0) {
#pragma unroll
        for (int r = 0; r < 4; r++)
          Cout[(size_t)(row0 + r) * N + col] = acc[mt][nt][r];
      } else {
        const int bb = row0 >> 11, s = row0 & 2047;
        if (col < 2048) {
          unsigned short* dst = (col < 1024) ? Qb : Kb;
          const int c = col & 1023;
          const size_t off = ((size_t)(bb * 16 + (c >> 6)) * 2048 + s) * 64 + (c & 63);
#pragma unroll
          for (int r = 0; r < 4; r++)
            dst[off + (size_t)r * 64] = f32_bf16(acc[mt][nt][r]);
        } else {
          const int c = col - 2048;
          // permute s within its 128-block: keep bits 6,5,1,0; bits 3,2 -> 4,3; bit 4 -> 2
          const int sl = s & 127;
          const int snew = (s & ~127) | (sl & 0x63) | ((sl & 0x0C) << 1) | ((sl & 0x10) >> 2);
          const size_t off = ((size_t)(bb * 16 + (c >> 6)) * 64 + (c & 63)) * 2048 + snew;
          bf16x4 pk;
#pragma unroll
          for (int r = 0; r < 4; r++) pk[r] = (__bf16)acc[mt][nt][r];
          *(bf16x4*)&VTb[off] = pk;
        }
      }
    }
  }
}

// ---------------- fused flash attention, S^T form, P-in-registers, double-buffered ----------------
// grid 512 = 16 q-tiles x 32 (b,h); block 512 = 8 waves = 4 wq (32 q-rows) x 2 wk (64 k-rows).
// The k-split halves per-wave LDS reads (K: 8 b128, V: 8 b128 per kt) vs the q-only split;
// wk halves combine O/l once at the end through the freed KV buffer.
// PV uses 16x16x32 MFMA: A = concat of the two consecutive QK C-fragments (pa8),
// B = one b128 V read (the VTb s-permutation makes both operands' k-relabeling
// identical: slot quad*8+j <-> phys k = p*32 + (j>=4)*16 + quad*4 + (j&3)).
// QK and PV stay interleaved per ntk-PAIR so only pa8[2] (8 VGPRs) is live at a time
// (pa[2][4] spilled: measured +16MB HBM WRITE_SIZE).
// blockIdx decode puts all 16 q-blocks of one (b,h) on the same XCD (bid%8 round-robin).
// One barrier per K-iteration: tile kt+2 is staged into the buffer consumed at iter kt.
__global__ void __launch_bounds__(512, 4) attn(const unsigned short* __restrict__ Qb,
                                               const unsigned short* __restrict__ Kb,
                                               const unsigned short* __restrict__ VTb,
                                               const float* __restrict__ mask,
                                               const float* __restrict__ emb,
                                               const int* __restrict__ mflag,
                                               unsigned short* __restrict__ ctx) {
  // two buffers, each: K tile (128x64) + V^T tile (64x128)
  __shared__ __align__(16) unsigned short KV[2][16384];
  __shared__ float biasLUT[512];

  const float LOG2E = 1.4426950408889634f;
  const float c1 = 0.125f * LOG2E;
  const float C2 = 10000.0f * LOG2E;
  const int tid = threadIdx.x, wave = tid >> 6, lane = tid & 63;
  const int l = lane & 15, quad = lane >> 4;
  const int wq = wave & 3, wk = wave >> 2;
  const int bh = blockIdx.x & 31, qt = blockIdx.x >> 5;
  const int b = bh >> 4, h = bh & 15;
  const int q0 = qt * 128;

  {
    int i = tid;  // 512 threads cover the 512-entry LUT exactly once
    int rel = i - 256;
    int rp = rel < 0 ? -rel : rel;
    int off = rp < 8 ? rp
                     : 8 + (rp >= 12) + (rp >= 16) + (rp >= 23) + (rp >= 32) +
                           (rp >= 46) + (rp >= 64) + (rp >= 91);
    int bucket = (rel > 0 ? 16 : 0) + off;
    biasLUT[i] = emb[bucket * 16 + h] * LOG2E;
  }
  const float satL = emb[15 * 16 + h] * LOG2E;
  const float satH = emb[31 * 16 + h] * LOG2E;
  const int masked = *mflag;

  const unsigned short* qb  = Qb  + ((size_t)(b * 16 + h) * 2048 + q0) * 64;
  const unsigned short* kb  = Kb  + (size_t)(b * 16 + h) * 2048 * 64;
  const unsigned short* vtb = VTb + (size_t)(b * 16 + h) * 64 * 2048;
  const float* mbase = mask + (size_t)b * 2048 * 2048;

  const int rw8 = lane >> 3, c8s = lane & 7;    // K/Q staging: 8 chunks/row
  const int rw16 = lane >> 4, c16 = lane & 15;  // V staging: 16 chunks/row

  // ---- prologue: Q -> buf1 K-region, tile0 K/V -> buf0 ----
#pragma unroll
  for (int j = 0; j < 2; j++) {
    int row = wave * 16 + j * 8 + rw8;
    gload16(qb + (size_t)row * 64 + ((c8s ^ (row & 7)) * 8), &KV[1][(wave * 16 + j * 8) * 64]);
  }
#pragma unroll
  for (int j = 0; j < 2; j++) {
    int row = wave * 16 + j * 8 + rw8;
    gload16(kb + (size_t)row * 64 + ((c8s ^ (row & 7)) * 8), &KV[0][(wave * 16 + j * 8) * 64]);
  }
#pragma unroll
  for (int j = 0; j < 2; j++) {
    int drow = wave * 8 + j * 4 + rw16;
    gload16(vtb + (size_t)drow * 2048 + ((c16 ^ (drow & 7)) * 8),
            &KV[0][8192 + (wave * 8 + j * 4) * 128]);
  }
  __syncthreads();

  // each wave reads its 32 Q rows (staged region of buf1)
  bf16x8 qf[2][2];
#pragma unroll
  for (int mtq = 0; mtq < 2; mtq++)
#pragma unroll
    for (int ks = 0; ks < 2; ks++) {
      int row = wq * 32 + mtq * 16 + l;
      qf[mtq][ks] = *(const bf16x8*)&KV[1][row * 64 + (((ks * 4 + quad) ^ (row & 7)) * 8)];
    }
  __syncthreads();  // Q reads complete before buf1 is overwritten with tile1

  // ---- stage tile1 -> buf1 ----
#pragma unroll
  for (int j = 0; j < 2; j++) {
    int row = wave * 16 + j * 8 + rw8;
    gload16(kb + (size_t)(128 + row) * 64 + ((c8s ^ (row & 7)) * 8),
            &KV[1][(wave * 16 + j * 8) * 64]);
  }
#pragma unroll
  for (int j = 0; j < 2; j++) {
    int drow = wave * 8 + j * 4 + rw16;
    gload16(vtb + (size_t)drow * 2048 + 128 + ((c16 ^ (drow & 7)) * 8),
            &KV[1][8192 + (wave * 8 + j * 4) * 128]);
  }

  float lr[2] = {0.f, 0.f};
  f32x4 Oa[2][4];
#pragma unroll
  for (int mtq = 0; mtq < 2; mtq++)
#pragma unroll
    for (int dt = 0; dt < 4; dt++) { f32x4 z = {0.f, 0.f, 0.f, 0.f}; Oa[mtq][dt] = z; }

  for (int kt = 0; kt < 16; kt++) {
    const int k0 = kt * 128;
    const unsigned short* Ks  = KV[kt & 1];
    const unsigned short* VTs = KV[kt & 1] + 8192;

    const int d0 = k0 - q0;
    const bool sat = (d0 >= 256) || (d0 <= -256);
    const float bias_u = d0 > 0 ? satH : satL;
    const int ibase = 256 + d0 + wk * 64 + quad * 4 - wq * 32 - l;

    // ---- interleaved per ntk-pair: S^T (2 k-slabs) then PV for those slabs ----
#pragma unroll
    for (int p = 0; p < 2; p++) {
      bf16x8 pa8[2];  // A-fragment for 16x16x32 PV: slots 0-3 from ntk even, 4-7 odd
#pragma unroll
      for (int t = 0; t < 2; t++) {
        const int ntk = p * 2 + t;
        int row = wk * 64 + ntk * 16 + l;
        bf16x8 kf0 = *(const bf16x8*)&Ks[row * 64 + ((quad ^ (row & 7)) * 8)];
        bf16x8 kf1 = *(const bf16x8*)&Ks[row * 64 + (((4 + quad) ^ (row & 7)) * 8)];
#pragma unroll
        for (int mtq = 0; mtq < 2; mtq++) {
          f32x4 s = {0.f, 0.f, 0.f, 0.f};
          s = __builtin_amdgcn_mfma_f32_16x16x32_bf16(kf0, qf[mtq][0], s, 0, 0, 0);
          s = __builtin_amdgcn_mfma_f32_16x16x32_bf16(kf1, qf[mtq][1], s, 0, 0, 0);

          const int ib = ibase + ntk * 16 - mtq * 16;
          if (!masked) {
            if (sat) {
#pragma unroll
              for (int r = 0; r < 4; r++) s[r] = fmaf(s[r], c1, bias_u);
            } else {
#pragma unroll
              for (int r = 0; r < 4; r++) s[r] = fmaf(s[r], c1, biasLUT[ib + r]);
            }
          } else {
            const int qg = q0 + wq * 32 + mtq * 16 + l;
            const int kg = k0 + wk * 64 + ntk * 16 + quad * 4;
            float4 mv4 = *(const float4*)&mbase[(size_t)qg * 2048 + kg];
#pragma unroll
            for (int r = 0; r < 4; r++) {
              float mv = r == 0 ? mv4.x : (r == 1 ? mv4.y : (r == 2 ? mv4.z : mv4.w));
              float bias = sat ? bias_u : biasLUT[ib + r];
              s[r] = fmaf(s[r], mv * c1, fmaf(mv, C2, bias - C2));
            }
          }
          float ls = 0.f;
#pragma unroll
          for (int r = 0; r < 4; r++) {
            float pv = __builtin_amdgcn_exp2f(s[r]);  // softmax shift-invariance: no max needed
            ls += pv;
            pa8[mtq][t * 4 + r] = (__bf16)pv;
          }
          lr[mtq] += ls;
        }
      }

      // ---- O += P V: one 16x16x32 MFMA per (dt,mtq); B straight from b128 ----
#pragma unroll
      for (int dt = 0; dt < 4; dt++) {
        int row = dt * 16 + l;
        bf16x8 w = *(const bf16x8*)&VTs[row * 128 + (((wk * 8 + p * 4 + quad) ^ (l & 7)) * 8)];
#pragma unroll
        for (int mtq = 0; mtq < 2; mtq++)
          Oa[mtq][dt] = __builtin_amdgcn_mfma_f32_16x16x32_bf16(pa8[mtq], w, Oa[mtq][dt], 0, 0, 0);
      }
    }

    // ---- one barrier: all reads of this buffer done + next tile's loads landed ----
    __syncthreads();
    if (kt + 2 < 16) {
      const int kn = (kt + 2) * 128;
      unsigned short* dst = (unsigned short*)KV[kt & 1];
#pragma unroll
      for (int j = 0; j < 2; j++) {
        int row = wave * 16 + j * 8 + rw8;
        gload16(kb + (size_t)(kn + row) * 64 + ((c8s ^ (row & 7)) * 8),
                &dst[(wave * 16 + j * 8) * 64]);
      }
#pragma unroll
      for (int j = 0; j < 2; j++) {
        int drow = wave * 8 + j * 4 + rw16;
        gload16(vtb + (size_t)drow * 2048 + kn + ((c16 ^ (drow & 7)) * 8),
                &dst[8192 + (wave * 8 + j * 4) * 128]);
      }
    }
  }

  // ---- cross-wave (wk) reduction through freed KV, then normalize + store ----
  float* Of = (float*)KV;       // 8192 floats = 32KB (q 0..127 x d 0..63)
  float* Lf = Of + 8192;        // 128 floats
  if (wk == 1) {
#pragma unroll
    for (int mtq = 0; mtq < 2; mtq++) {
      float v = lr[mtq];
      v += __shfl_xor(v, 16);
      v += __shfl_xor(v, 32);
      if (quad == 0) Lf[wq * 32 + mtq * 16 + l] = v;
#pragma unroll
      for (int dt = 0; dt < 4; dt++)
#pragma unroll
        for (int r = 0; r < 4; r++)
          Of[(wq * 32 + mtq * 16 + quad * 4 + r) * 64 + dt * 16 + l] = Oa[mtq][dt][r];
    }
  }
  __syncthreads();
  if (wk == 0) {
#pragma unroll
    for (int mtq = 0; mtq < 2; mtq++) {
      float v = lr[mtq];
      v += __shfl_xor(v, 16);
      v += __shfl_xor(v, 32);
      v += Lf[wq * 32 + mtq * 16 + l];
      const float inv = 1.0f / v;
#pragma unroll
      for (int r = 0; r < 4; r++) {
        float i_bc = bcast_lane(inv, quad * 4 + r);
        const int qg = q0 + wq * 32 + mtq * 16 + quad * 4 + r;
#pragma unroll
        for (int dt = 0; dt < 4; dt++) {
          float o = Oa[mtq][dt][r] +
                    Of[(wq * 32 + mtq * 16 + quad * 4 + r) * 64 + dt * 16 + l];
          ctx[(size_t)(b * 2048 + qg) * 1024 + h * 64 + dt * 16 + l] = f32_bf16(o * i_bc);
        }
      }
    }
  }
}

// ---------------- launch ----------------
extern "C" void kernel_launch(void* const* d_in, const int* in_sizes, int n_in,
                              void* d_out, int out_size, void* d_ws, size_t ws_size,
                              hipStream_t stream) {
  const float* hs   = (const float*)d_in[0];
  const float* mask = (const float*)d_in[1];
  const float* wqkv = (const float*)d_in[2];
  const float* wo   = (const float*)d_in[3];
  const float* emb  = (const float*)d_in[4];
  float* out = (float*)d_out;

  char* ws = (char*)d_ws;
  unsigned short* hB  = (unsigned short*)(ws);               //  8 MB (alias ctx)
  unsigned short* ctx = (unsigned short*)(ws);               //  alias
  unsigned short* wqT = (unsigned short*)(ws + 8388608);     //  6 MB
  unsigned short* woT = (unsigned short*)(ws + 14680064);    //  2 MB
  unsigned short* Qb  = (unsigned short*)(ws + 16777216);    //  8 MB  [b,h,s,d]
  unsigned short* Kb  = (unsigned short*)(ws + 25165824);    //  8 MB  [b,h,s,d]
  unsigned short* VTb = (unsigned short*)(ws + 33554432);    //  8 MB  [b,h,d,s] (s-permuted)
  int* mflag          = (int*)(ws + 41943040);
  if (ws_size < 41943044) return;

  hipMemsetAsync(mflag, 0, 4, stream);
  cast_bf16<<<4096, 256, 0, stream>>>(hs, hB);
  transpose_cast<<<dim3(16, 48), 256, 0, stream>>>(wqkv, wqT, 1024, 3072);
  transpose_cast<<<dim3(16, 16), 256, 0, stream>>>(wo, woT, 1024, 1024);
  mask_check<<<8192, 256, 0, stream>>>(mask, mflag);
  gemm_bt<2, 128><<<dim3(32, 24), 256, 0, stream>>>(hB, wqT, nullptr, Qb, Kb, VTb, 4096, 3072, 1024);
  attn<<<512, 512, 0, stream>>>(Qb, Kb, VTb, mask, emb, mflag, ctx);
  gemm_bt<0, 64><<<dim3(32, 16), 256, 0, stream>>>(ctx, woT, out, nullptr, nullptr, nullptr, 4096, 1024, 1024);
}

// Round 8
// 204.851 us; speedup vs baseline: 1.1409x; 1.0012x over previous
//
#include <hip/hip_runtime.h>
#include <cstdint>

#define DEV static __device__ __forceinline__

typedef __bf16 bf16x8 __attribute__((ext_vector_type(8)));
typedef __bf16 bf16x4 __attribute__((ext_vector_type(4)));
typedef short  s16x4  __attribute__((ext_vector_type(4)));
typedef float  f32x4  __attribute__((ext_vector_type(4)));

#define VM_WAIT4 asm volatile("s_waitcnt vmcnt(4)" ::: "memory")
#define VM_WAIT3 asm volatile("s_waitcnt vmcnt(3)" ::: "memory")
#define VM_WAIT0 asm volatile("s_waitcnt vmcnt(0)" ::: "memory")

DEV unsigned short f32_bf16(float f) {
  union { float f; unsigned u; } v; v.f = f;
  unsigned r = v.u + 0x7FFFu + ((v.u >> 16) & 1u);
  return (unsigned short)(r >> 16);
}

DEV void gload16(const void* g, void* lds) {
  __builtin_amdgcn_global_load_lds((__attribute__((address_space(1))) void*)g,
                                   (__attribute__((address_space(3))) void*)lds,
                                   16, 0, 0);
}

DEV float bcast_lane(float v, int srclane) {
  union { float f; int i; } u; u.f = v;
  u.i = __builtin_amdgcn_ds_bpermute(srclane << 2, u.i);
  return u.f;
}

// ---------------- fused prologue: cast + 2x transpose-cast + mask check ----------------
// One kernel, block-range dispatch (branch is block-uniform):
//   [0, 4096)        cast hs fp32 -> hB bf16            (16 MB read)
//   [4096, 4864)     transpose-cast wqkv -> wqT          (12 MB read)
//   [4864, 5120)     transpose-cast wo   -> woT          ( 4 MB read)
//   [5120, 13312)    mask uniformity check -> mflag      (32 MB read)
// Replaces 4 graph nodes with 1 (launch-gap elimination); all four jobs are
// mutually independent and all must precede gemm1/attn/gemm2 on the stream.
DEV void transpose_body(const float* __restrict__ W, unsigned short* __restrict__ WT,
                        int K, int N, int k0, int n0, float (*t)[65]) {
  int tn = threadIdx.x & 63, tk = threadIdx.x >> 6;
#pragma unroll
  for (int i = 0; i < 64; i += 4)
    t[tk + i][tn] = W[(size_t)(k0 + tk + i) * N + n0 + tn];
  __syncthreads();
  int k2 = (threadIdx.x & 31) * 2, n = threadIdx.x >> 5;
#pragma unroll
  for (int i = 0; i < 64; i += 8) {
    int nn = n + i;
    unsigned o = (unsigned)f32_bf16(t[k2][nn]) | ((unsigned)f32_bf16(t[k2 + 1][nn]) << 16);
    *(unsigned*)&WT[(size_t)(n0 + nn) * K + k0 + k2] = o;
  }
}

__global__ void __launch_bounds__(256) prologue(const float* __restrict__ hs,
                                                unsigned short* __restrict__ hB,
                                                const float* __restrict__ wqkv,
                                                unsigned short* __restrict__ wqT,
                                                const float* __restrict__ wo,
                                                unsigned short* __restrict__ woT,
                                                const float* __restrict__ mask,
                                                int* __restrict__ flag) {
  __shared__ float t[64][65];
  const int bid = blockIdx.x;
  if (bid < 4096) {
    int i = bid * 256 + threadIdx.x;
    float4 v = ((const float4*)hs)[i];
    uint2 o;
    o.x = (unsigned)f32_bf16(v.x) | ((unsigned)f32_bf16(v.y) << 16);
    o.y = (unsigned)f32_bf16(v.z) | ((unsigned)f32_bf16(v.w) << 16);
    ((uint2*)hB)[i] = o;
  } else if (bid < 4864) {
    int tt = bid - 4096;
    transpose_body(wqkv, wqT, 1024, 3072, (tt & 15) * 64, (tt >> 4) * 64, t);
  } else if (bid < 5120) {
    int tt = bid - 4864;
    transpose_body(wo, woT, 1024, 1024, (tt & 15) * 64, (tt >> 4) * 64, t);
  } else {
    size_t i = ((size_t)(bid - 5120) * 256 + threadIdx.x) * 4;
    float4 v = *(const float4*)(mask + i);
    if (v.x != 1.0f || v.y != 1.0f || v.z != 1.0f || v.w != 1.0f) atomicOr(flag, 1);
  }
}

// ---------------- GEMM: C[M][N] = A[M][K] * BT[N][K]^T ----------------
// MODE 0: fp32 C. MODE 2: scatter Qb/Kb [b,h,s,d], VTb [b,h,d,s] (TN must be 128).
// VTb s-index is permuted within each 128-block (keep bits 6,5,1,0; 3,2->4,3; 4->2) so the
// attn PV step can feed one b128 V read directly as the B-operand of a 16x16x32 MFMA
// whose A-operand is the concat of two consecutive QK C-fragments.
// 3-buffer, 2-tiles-ahead pipeline with counted vmcnt + raw s_barrier. Measured
// NEUTRAL vs single-buffer (gemm is LDS-read/issue-bound, not latency-bound:
// 8 ds_read_b128 x 12 waves/CU ~= 37K LDS-pipe cycles > 30K MFMA cycles); kept
// because it passed verification and costs nothing.
template <int MODE, int TN>
__global__ void __launch_bounds__(256) gemm_bt(const unsigned short* __restrict__ A,
                                               const unsigned short* __restrict__ BT,
                                               float* __restrict__ Cout,
                                               unsigned short* __restrict__ Qb,
                                               unsigned short* __restrict__ Kb,
                                               unsigned short* __restrict__ VTb,
                                               int M, int N, int K) {
  constexpr int NT = TN / 32;
  __shared__ __align__(16) unsigned short As[3][128 * 32];
  __shared__ __align__(16) unsigned short Bs[3][TN * 32];
  const int tid = threadIdx.x, wave = tid >> 6, lane = tid & 63;
  const int l = lane & 15, quad = lane >> 4;
  const int wm = (wave & 1) * 64, wn = (wave >> 1) * (TN >> 1);
  const int bm = blockIdx.x, bn = blockIdx.y;

  const int srowA = wave * 32 + (lane >> 2);
  const int sswzA = ((lane & 3) ^ (srowA & 3)) * 8;
  const int srowB = (TN == 128) ? srowA : (wave * 16 + (lane >> 2));
  const int sswzB = ((lane & 3) ^ (srowB & 3)) * 8;
  const unsigned short* pA = A + (size_t)(bm * 128 + srowA) * K + sswzA;
  const unsigned short* pB = BT + (size_t)(bn * TN + srowB) * K + sswzB;
  const int ldsA0 = (wave * 32) * 32;
  const int ldsA1 = (wave * 32 + 16) * 32;
  const int ldsB0 = (TN == 128 ? wave * 32 : wave * 16) * 32;
  const int ldsB1 = (wave * 32 + 16) * 32;  // TN==128 only

  auto stage = [&](int buf) {
    gload16(pA, &As[buf][ldsA0]);
    gload16(pA + (size_t)16 * K, &As[buf][ldsA1]);
    gload16(pB, &Bs[buf][ldsB0]);
    if (TN == 128) gload16(pB + (size_t)16 * K, &Bs[buf][ldsB1]);
    pA += 32; pB += 32;
  };

  f32x4 acc[4][NT];
#pragma unroll
  for (int i = 0; i < 4; i++)
#pragma unroll
    for (int j = 0; j < NT; j++) { f32x4 z = {0.f, 0.f, 0.f, 0.f}; acc[i][j] = z; }

  // prologue: 2 tiles in flight
  stage(0);
  stage(1);

  const int nkt = K >> 5;
  for (int kt = 0; kt < nkt; kt++) {
    const int cur = kt % 3;
    // tile kt's loads (this wave's oldest LOADS) must have landed; tile kt+1's stay in flight
    if (kt != nkt - 1) {
      if (TN == 128) { VM_WAIT4; } else { VM_WAIT3; }
    } else {
      VM_WAIT0;
    }
    __builtin_amdgcn_s_barrier();
    __builtin_amdgcn_sched_barrier(0);
    if (kt + 2 < nkt) stage((kt + 2) % 3);
    bf16x8 af[4], bv[NT];
#pragma unroll
    for (int mt = 0; mt < 4; mt++) {
      int r = wm + mt * 16 + l;
      af[mt] = *(const bf16x8*)&As[cur][r * 32 + ((quad ^ (r & 3)) * 8)];
    }
#pragma unroll
    for (int nt = 0; nt < NT; nt++) {
      int r = wn + nt * 16 + l;
      bv[nt] = *(const bf16x8*)&Bs[cur][r * 32 + ((quad ^ (r & 3)) * 8)];
    }
#pragma unroll
    for (int mt = 0; mt < 4; mt++)
#pragma unroll
      for (int nt = 0; nt < NT; nt++)
        acc[mt][nt] = __builtin_amdgcn_mfma_f32_16x16x32_bf16(af[mt], bv[nt], acc[mt][nt], 0, 0, 0);
  }

  // epilogue: C/D layout col = lane&15, row = quad*4 + r
#pragma unroll
  for (int nt = 0; nt < NT; nt++) {
    const int col = bn * TN + wn + nt * 16 + l;
#pragma unroll
    for (int mt = 0; mt < 4; mt++) {
      const int row0 = bm * 128 + wm + mt * 16 + quad * 4;
      if (MODE == 0) {
#pragma unroll
        for (int r = 0; r < 4; r++)
          Cout[(size_t)(row0 + r) * N + col] = acc[mt][nt][r];
      } else {
        const int bb = row0 >> 11, s = row0 & 2047;
        if (col < 2048) {
          unsigned short* dst = (col < 1024) ? Qb : Kb;
          const int c = col & 1023;
          const size_t off = ((size_t)(bb * 16 + (c >> 6)) * 2048 + s) * 64 + (c & 63);
#pragma unroll
          for (int r = 0; r < 4; r++)
            dst[off + (size_t)r * 64] = f32_bf16(acc[mt][nt][r]);
        } else {
          const int c = col - 2048;
          // permute s within its 128-block: keep bits 6,5,1,0; bits 3,2 -> 4,3; bit 4 -> 2
          const int sl = s & 127;
          const int snew = (s & ~127) | (sl & 0x63) | ((sl & 0x0C) << 1) | ((sl & 0x10) >> 2);
          const size_t off = ((size_t)(bb * 16 + (c >> 6)) * 64 + (c & 63)) * 2048 + snew;
          bf16x4 pk;
#pragma unroll
          for (int r = 0; r < 4; r++) pk[r] = (__bf16)acc[mt][nt][r];
          *(bf16x4*)&VTb[off] = pk;
        }
      }
    }
  }
}

// ---------------- fused flash attention, S^T form, P-in-registers, double-buffered ----------------
// grid 512 = 16 q-tiles x 32 (b,h); block 512 = 8 waves = 4 wq (32 q-rows) x 2 wk (64 k-rows).
// The k-split halves per-wave LDS reads (K: 8 b128, V: 8 b128 per kt) vs the q-only split;
// wk halves combine O/l once at the end through the freed KV buffer.
// PV uses 16x16x32 MFMA: A = concat of the two consecutive QK C-fragments (pa8),
// B = one b128 V read (the VTb s-permutation makes both operands' k-relabeling
// identical: slot quad*8+j <-> phys k = p*32 + (j>=4)*16 + quad*4 + (j&3)).
// QK and PV stay interleaved per ntk-PAIR so only pa8[2] (8 VGPRs) is live at a time
// (pa[2][4] spilled: measured +16MB HBM WRITE_SIZE).
// s_setprio(1) wraps the MFMA clusters (T5): waves at the MFMA phase get scheduler
// preference over waves issuing softmax VALU / staging — pays only because the
// interleaved phases give waves on one SIMD different roles at any instant.
// blockIdx decode puts all 16 q-blocks of one (b,h) on the same XCD (bid%8 round-robin).
// One barrier per K-iteration: tile kt+2 is staged into the buffer consumed at iter kt.
__global__ void __launch_bounds__(512, 4) attn(const unsigned short* __restrict__ Qb,
                                               const unsigned short* __restrict__ Kb,
                                               const unsigned short* __restrict__ VTb,
                                               const float* __restrict__ mask,
                                               const float* __restrict__ emb,
                                               const int* __restrict__ mflag,
                                               unsigned short* __restrict__ ctx) {
  // two buffers, each: K tile (128x64) + V^T tile (64x128)
  __shared__ __align__(16) unsigned short KV[2][16384];
  __shared__ float biasLUT[512];

  const float LOG2E = 1.4426950408889634f;
  const float c1 = 0.125f * LOG2E;
  const float C2 = 10000.0f * LOG2E;
  const int tid = threadIdx.x, wave = tid >> 6, lane = tid & 63;
  const int l = lane & 15, quad = lane >> 4;
  const int wq = wave & 3, wk = wave >> 2;
  const int bh = blockIdx.x & 31, qt = blockIdx.x >> 5;
  const int b = bh >> 4, h = bh & 15;
  const int q0 = qt * 128;

  {
    int i = tid;  // 512 threads cover the 512-entry LUT exactly once
    int rel = i - 256;
    int rp = rel < 0 ? -rel : rel;
    int off = rp < 8 ? rp
                     : 8 + (rp >= 12) + (rp >= 16) + (rp >= 23) + (rp >= 32) +
                           (rp >= 46) + (rp >= 64) + (rp >= 91);
    int bucket = (rel > 0 ? 16 : 0) + off;
    biasLUT[i] = emb[bucket * 16 + h] * LOG2E;
  }
  const float satL = emb[15 * 16 + h] * LOG2E;
  const float satH = emb[31 * 16 + h] * LOG2E;
  const int masked = *mflag;

  const unsigned short* qb  = Qb  + ((size_t)(b * 16 + h) * 2048 + q0) * 64;
  const unsigned short* kb  = Kb  + (size_t)(b * 16 + h) * 2048 * 64;
  const unsigned short* vtb = VTb + (size_t)(b * 16 + h) * 64 * 2048;
  const float* mbase = mask + (size_t)b * 2048 * 2048;

  const int rw8 = lane >> 3, c8s = lane & 7;    // K/Q staging: 8 chunks/row
  const int rw16 = lane >> 4, c16 = lane & 15;  // V staging: 16 chunks/row

  // ---- prologue: Q -> buf1 K-region, tile0 K/V -> buf0 ----
#pragma unroll
  for (int j = 0; j < 2; j++) {
    int row = wave * 16 + j * 8 + rw8;
    gload16(qb + (size_t)row * 64 + ((c8s ^ (row & 7)) * 8), &KV[1][(wave * 16 + j * 8) * 64]);
  }
#pragma unroll
  for (int j = 0; j < 2; j++) {
    int row = wave * 16 + j * 8 + rw8;
    gload16(kb + (size_t)row * 64 + ((c8s ^ (row & 7)) * 8), &KV[0][(wave * 16 + j * 8) * 64]);
  }
#pragma unroll
  for (int j = 0; j < 2; j++) {
    int drow = wave * 8 + j * 4 + rw16;
    gload16(vtb + (size_t)drow * 2048 + ((c16 ^ (drow & 7)) * 8),
            &KV[0][8192 + (wave * 8 + j * 4) * 128]);
  }
  __syncthreads();

  // each wave reads its 32 Q rows (staged region of buf1)
  bf16x8 qf[2][2];
#pragma unroll
  for (int mtq = 0; mtq < 2; mtq++)
#pragma unroll
    for (int ks = 0; ks < 2; ks++) {
      int row = wq * 32 + mtq * 16 + l;
      qf[mtq][ks] = *(const bf16x8*)&KV[1][row * 64 + (((ks * 4 + quad) ^ (row & 7)) * 8)];
    }
  __syncthreads();  // Q reads complete before buf1 is overwritten with tile1

  // ---- stage tile1 -> buf1 ----
#pragma unroll
  for (int j = 0; j < 2; j++) {
    int row = wave * 16 + j * 8 + rw8;
    gload16(kb + (size_t)(128 + row) * 64 + ((c8s ^ (row & 7)) * 8),
            &KV[1][(wave * 16 + j * 8) * 64]);
  }
#pragma unroll
  for (int j = 0; j < 2; j++) {
    int drow = wave * 8 + j * 4 + rw16;
    gload16(vtb + (size_t)drow * 2048 + 128 + ((c16 ^ (drow & 7)) * 8),
            &KV[1][8192 + (wave * 8 + j * 4) * 128]);
  }

  float lr[2] = {0.f, 0.f};
  f32x4 Oa[2][4];
#pragma unroll
  for (int mtq = 0; mtq < 2; mtq++)
#pragma unroll
    for (int dt = 0; dt < 4; dt++) { f32x4 z = {0.f, 0.f, 0.f, 0.f}; Oa[mtq][dt] = z; }

  for (int kt = 0; kt < 16; kt++) {
    const int k0 = kt * 128;
    const unsigned short* Ks  = KV[kt & 1];
    const unsigned short* VTs = KV[kt & 1] + 8192;

    const int d0 = k0 - q0;
    const bool sat = (d0 >= 256) || (d0 <= -256);
    const float bias_u = d0 > 0 ? satH : satL;
    const int ibase = 256 + d0 + wk * 64 + quad * 4 - wq * 32 - l;

    // ---- interleaved per ntk-pair: S^T (2 k-slabs) then PV for those slabs ----
#pragma unroll
    for (int p = 0; p < 2; p++) {
      bf16x8 pa8[2];  // A-fragment for 16x16x32 PV: slots 0-3 from ntk even, 4-7 odd
#pragma unroll
      for (int t = 0; t < 2; t++) {
        const int ntk = p * 2 + t;
        int row = wk * 64 + ntk * 16 + l;
        bf16x8 kf0 = *(const bf16x8*)&Ks[row * 64 + ((quad ^ (row & 7)) * 8)];
        bf16x8 kf1 = *(const bf16x8*)&Ks[row * 64 + (((4 + quad) ^ (row & 7)) * 8)];
#pragma unroll
        for (int mtq = 0; mtq < 2; mtq++) {
          f32x4 s = {0.f, 0.f, 0.f, 0.f};
          __builtin_amdgcn_s_setprio(1);
          s = __builtin_amdgcn_mfma_f32_16x16x32_bf16(kf0, qf[mtq][0], s, 0, 0, 0);
          s = __builtin_amdgcn_mfma_f32_16x16x32_bf16(kf1, qf[mtq][1], s, 0, 0, 0);
          __builtin_amdgcn_s_setprio(0);

          const int ib = ibase + ntk * 16 - mtq * 16;
          if (!masked) {
            if (sat) {
#pragma unroll
              for (int r = 0; r < 4; r++) s[r] = fmaf(s[r], c1, bias_u);
            } else {
#pragma unroll
              for (int r = 0; r < 4; r++) s[r] = fmaf(s[r], c1, biasLUT[ib + r]);
            }
          } else {
            const int qg = q0 + wq * 32 + mtq * 16 + l;
            const int kg = k0 + wk * 64 + ntk * 16 + quad * 4;
            float4 mv4 = *(const float4*)&mbase[(size_t)qg * 2048 + kg];
#pragma unroll
            for (int r = 0; r < 4; r++) {
              float mv = r == 0 ? mv4.x : (r == 1 ? mv4.y : (r == 2 ? mv4.z : mv4.w));
              float bias = sat ? bias_u : biasLUT[ib + r];
              s[r] = fmaf(s[r], mv * c1, fmaf(mv, C2, bias - C2));
            }
          }
          float ls = 0.f;
#pragma unroll
          for (int r = 0; r < 4; r++) {
            float pv = __builtin_amdgcn_exp2f(s[r]);  // softmax shift-invariance: no max needed
            ls += pv;
            pa8[mtq][t * 4 + r] = (__bf16)pv;
          }
          lr[mtq] += ls;
        }
      }

      // ---- O += P V: one 16x16x32 MFMA per (dt,mtq); B straight from b128 ----
      __builtin_amdgcn_s_setprio(1);
#pragma unroll
      for (int dt = 0; dt < 4; dt++) {
        int row = dt * 16 + l;
        bf16x8 w = *(const bf16x8*)&VTs[row * 128 + (((wk * 8 + p * 4 + quad) ^ (l & 7)) * 8)];
#pragma unroll
        for (int mtq = 0; mtq < 2; mtq++)
          Oa[mtq][dt] = __builtin_amdgcn_mfma_f32_16x16x32_bf16(pa8[mtq], w, Oa[mtq][dt], 0, 0, 0);
      }
      __builtin_amdgcn_s_setprio(0);
    }

    // ---- one barrier: all reads of this buffer done + next tile's loads landed ----
    __syncthreads();
    if (kt + 2 < 16) {
      const int kn = (kt + 2) * 128;
      unsigned short* dst = (unsigned short*)KV[kt & 1];
#pragma unroll
      for (int j = 0; j < 2; j++) {
        int row = wave * 16 + j * 8 + rw8;
        gload16(kb + (size_t)(kn + row) * 64 + ((c8s ^ (row & 7)) * 8),
                &dst[(wave * 16 + j * 8) * 64]);
      }
#pragma unroll
      for (int j = 0; j < 2; j++) {
        int drow = wave * 8 + j * 4 + rw16;
        gload16(vtb + (size_t)drow * 2048 + kn + ((c16 ^ (drow & 7)) * 8),
                &dst[8192 + (wave * 8 + j * 4) * 128]);
      }
    }
  }

  // ---- cross-wave (wk) reduction through freed KV, then normalize + store ----
  float* Of = (float*)KV;       // 8192 floats = 32KB (q 0..127 x d 0..63)
  float* Lf = Of + 8192;        // 128 floats
  if (wk == 1) {
#pragma unroll
    for (int mtq = 0; mtq < 2; mtq++) {
      float v = lr[mtq];
      v += __shfl_xor(v, 16);
      v += __shfl_xor(v, 32);
      if (quad == 0) Lf[wq * 32 + mtq * 16 + l] = v;
#pragma unroll
      for (int dt = 0; dt < 4; dt++)
#pragma unroll
        for (int r = 0; r < 4; r++)
          Of[(wq * 32 + mtq * 16 + quad * 4 + r) * 64 + dt * 16 + l] = Oa[mtq][dt][r];
    }
  }
  __syncthreads();
  if (wk == 0) {
#pragma unroll
    for (int mtq = 0; mtq < 2; mtq++) {
      float v = lr[mtq];
      v += __shfl_xor(v, 16);
      v += __shfl_xor(v, 32);
      v += Lf[wq * 32 + mtq * 16 + l];
      const float inv = 1.0f / v;
#pragma unroll
      for (int r = 0; r < 4; r++) {
        float i_bc = bcast_lane(inv, quad * 4 + r);
        const int qg = q0 + wq * 32 + mtq * 16 + quad * 4 + r;
#pragma unroll
        for (int dt = 0; dt < 4; dt++) {
          float o = Oa[mtq][dt][r] +
                    Of[(wq * 32 + mtq * 16 + quad * 4 + r) * 64 + dt * 16 + l];
          ctx[(size_t)(b * 2048 + qg) * 1024 + h * 64 + dt * 16 + l] = f32_bf16(o * i_bc);
        }
      }
    }
  }
}

// ---------------- launch ----------------
extern "C" void kernel_launch(void* const* d_in, const int* in_sizes, int n_in,
                              void* d_out, int out_size, void* d_ws, size_t ws_size,
                              hipStream_t stream) {
  const float* hs   = (const float*)d_in[0];
  const float* mask = (const float*)d_in[1];
  const float* wqkv = (const float*)d_in[2];
  const float* wo   = (const float*)d_in[3];
  const float* emb  = (const float*)d_in[4];
  float* out = (float*)d_out;

  char* ws = (char*)d_ws;
  unsigned short* hB  = (unsigned short*)(ws);               //  8 MB (alias ctx)
  unsigned short* ctx = (unsigned short*)(ws);               //  alias
  unsigned short* wqT = (unsigned short*)(ws + 8388608);     //  6 MB
  unsigned short* woT = (unsigned short*)(ws + 14680064);    //  2 MB
  unsigned short* Qb  = (unsigned short*)(ws + 16777216);    //  8 MB  [b,h,s,d]
  unsigned short* Kb  = (unsigned short*)(ws + 25165824);    //  8 MB  [b,h,s,d]
  unsigned short* VTb = (unsigned short*)(ws + 33554432);    //  8 MB  [b,h,d,s] (s-permuted)
  int* mflag          = (int*)(ws + 41943040);
  if (ws_size < 41943044) return;

  hipMemsetAsync(mflag, 0, 4, stream);
  prologue<<<13312, 256, 0, stream>>>(hs, hB, wqkv, wqT, wo, woT, mask, mflag);
  gemm_bt<2, 128><<<dim3(32, 24), 256, 0, stream>>>(hB, wqT, nullptr, Qb, Kb, VTb, 4096, 3072, 1024);
  attn<<<512, 512, 0, stream>>>(Qb, Kb, VTb, mask, emb, mflag, ctx);
  gemm_bt<0, 64><<<dim3(32, 16), 256, 0, stream>>>(ctx, woT, out, nullptr, nullptr, nullptr, 4096, 1024, 1024);
}